// Round 5
// baseline (2797.862 us; speedup 1.0000x reference)
//
#include <hip/hip_runtime.h>
#include <hip/hip_cooperative_groups.h>
#include <math.h>

namespace cg = cooperative_groups;

#define B_    32
#define T_    21
#define STEPS 20
#define V_    10000
#define E_    512
#define A_    512
#define L_    512
#define P_    196
#define ENC_  2048
#define XW_   3072   // bf16 X' row: [emb(512) | awe*beta(2048) | h(512)]

// ---- workspace layout (float offsets), total 8,384,576 fl = 33.5 MB ----
#define WS_ORD    0
#define WS_SLEN   32
#define WS_CBUF   64        // 2*16384 fp32 c double-buffer
#define WS_CB0    32832     // bf16 32*512 (c0, prologue)      -> 4096 fl
#define WS_CBALL  36928     // bf16 20*32*512 (c per step)     -> 163840 fl
#define WS_XB     200768    // bf16 2 x 32*3072 (double-buffered) -> 98304 fl
#define WS_A2S    299072    // 32*512
#define WS_BETA   315456    // 32*2048
#define WS_ESH    380992    // 32*256
#define WS_A1B    389184    // bf16 6272*512 -> 1605632 fl
#define WS_WZP    1994816   // bf16 128nt*96kt*64*8 -> 3145728 fl
#define WS_WCP    5140544   // bf16 792nt*16kt*64*8 -> 3244032 fl  (end 8384576)
// prologue-only aliases (stream-ordered, dead before the pack kernels write):
#define WS_MEAN   (WS_WZP)           // 65536 fl; dead after sg_partial
#define WS_PH     (WS_WZP + 65536)   // 524288 fl; dead after k_h0c0
#define WS_WEAT   (WS_WCP)           // 524288 fl; dead after k_a1_mfma

// ---- output layout (float offsets) ----
#define OUT_PRED  0
#define OUT_ALPHA 6400000
#define OUT_ORDER 6525440

typedef __attribute__((ext_vector_type(8))) short bf16x8;
typedef __attribute__((ext_vector_type(4))) float f32x4;
typedef unsigned short ushort_t;

__device__ inline unsigned f2bf2(float lo, float hi) {
    unsigned a = __float_as_uint(lo), b = __float_as_uint(hi);
    a = (a + 0x7FFFu + ((a >> 16) & 1u)) >> 16;
    b = (b + 0x7FFFu + ((b >> 16) & 1u)) >> 16;
    return a | (b << 16);
}
__device__ inline ushort_t f2bf(float f) {
    unsigned u = __float_as_uint(f);
    return (ushort_t)((u + 0x7FFFu + ((u >> 16) & 1u)) >> 16);
}
__device__ inline float bfu_lo(unsigned u) { return __uint_as_float(u << 16); }
__device__ inline float bfu_hi(unsigned u) { return __uint_as_float(u & 0xFFFF0000u); }

// ============ order / lengths ============
__global__ void k_order(const int* __restrict__ seqs, int* __restrict__ ord,
                        int* __restrict__ slen, float* __restrict__ out_ord)
{
    __shared__ int len[B_];
    int i = threadIdx.x;
    if (i < B_) {
        int c = 0;
        for (int t = 0; t < T_; ++t) c += (seqs[i * T_ + t] != 0) ? 1 : 0;
        len[i] = c;
    }
    __syncthreads();
    if (i < B_) {
        int li = len[i], r = 0;
        for (int j = 0; j < B_; ++j) {
            int lj = len[j];
            if (lj > li || (lj == li && j < i)) ++r;
        }
        ord[r] = i; slen[r] = li - 1; out_ord[r] = (float)i;
    }
}

// ============ mean-pool encoder (sorted) ============
__global__ void k_mean(const float* __restrict__ enc, const int* __restrict__ ord,
                       float* __restrict__ mean)
{
    int tid = blockIdx.x * 256 + threadIdx.x;
    int b = tid >> 11, e = tid & 2047;
    const float* row = enc + (size_t)ord[b] * (P_ * ENC_) + e;
    float s = 0.f;
    for (int p = 0; p < P_; ++p) s += row[(size_t)p * ENC_];
    mean[tid] = s * (1.0f / 196.0f);
}

// ============ cast + transpose Wea -> WeaT bf16 [512][2048] ============
__global__ void k_castWT(const float* __restrict__ Wea, ushort_t* __restrict__ WT)
{
    int tid = blockIdx.x * 256 + threadIdx.x;
    int n = tid >> 11, k = tid & 2047;
    WT[tid] = f2bf(Wea[(size_t)k * 512 + n]);
}

// ============ prologue skinny GEMM partial (fp32) for h0/c0 ============
__global__ void sg_partial(const float* __restrict__ X, const float* __restrict__ W,
                           float* __restrict__ part, int K, int N, int kchunk, int chunk_ofs)
{
    const int n = blockIdx.x * 256 + threadIdx.x;
    const int c = blockIdx.y;
    const int bh = blockIdx.z;
    const int k0 = c * kchunk;
    int k1 = k0 + kchunk; if (k1 > K) k1 = K;
    float acc[16];
#pragma unroll
    for (int b = 0; b < 16; ++b) acc[b] = 0.f;
    if (n < N) {
        const float* Xb = X + (size_t)(bh * 16) * K;
        for (int k = k0; k < k1; k += 4) {
            float w0 = W[(size_t)(k + 0) * N + n];
            float w1 = W[(size_t)(k + 1) * N + n];
            float w2 = W[(size_t)(k + 2) * N + n];
            float w3 = W[(size_t)(k + 3) * N + n];
#pragma unroll
            for (int b = 0; b < 16; ++b) {
                const float4 xv = *reinterpret_cast<const float4*>(&Xb[(size_t)b * K + k]);
                acc[b] += xv.x * w0 + xv.y * w1 + xv.z * w2 + xv.w * w3;
            }
        }
        float* po = part + (size_t)(chunk_ofs + c) * (B_ * (size_t)N) + (size_t)(bh * 16) * N;
#pragma unroll
        for (int b = 0; b < 16; ++b) po[(size_t)b * N + n] = acc[b];
    }
}

// ============ h0/c0 combine: c0 fp32 + cB0 bf16 + h0 into XB0 h-section ============
__global__ void k_h0c0(const float* __restrict__ ph, const float* __restrict__ bim,
                       const float* __restrict__ bic, float* __restrict__ c0,
                       ushort_t* __restrict__ cB0, ushort_t* __restrict__ XB0)
{
    int tid = blockIdx.x * 256 + threadIdx.x;
    int half = tid >> 14;
    int idx = tid & 16383;
    int l = idx & 511, b = idx >> 9;
    int cofs = half ? 16 : 0;
    float s = 0.f;
    for (int c = 0; c < 16; ++c) s += ph[(size_t)(cofs + c) * (B_ * 512) + idx];
    if (half) {
        float cv = s + bic[l];
        c0[idx] = cv;
        cB0[idx] = f2bf(cv);
    } else {
        XB0[(size_t)b * XW_ + 2560 + l] = f2bf(s + bim[l]);
    }
}

// ============ a1 MFMA, 64-row M-tiles (grid 98x4 = 392 blocks) ============
__global__ __launch_bounds__(256) void k_a1_mfma(
    const float* __restrict__ enc, const ushort_t* __restrict__ WeaT,
    const float* __restrict__ bea, const int* __restrict__ ord,
    ushort_t* __restrict__ a1b)
{
    __shared__ ushort_t As[2][64 * 40];
    __shared__ ushort_t Bs[2][128 * 40];
    const int tid = threadIdx.x;
    const int lane = tid & 63, wave = tid >> 6;
    const int m0 = blockIdx.x * 64;
    const int n0 = blockIdx.y * 128;

    const int arA = tid >> 2, akA = (tid & 3) * 8;
    const int gA = m0 + arA;
    const float* Ag = enc + ((size_t)ord[gA / P_] * P_ + (gA % P_)) * ENC_ + akA;
    const int cb0 = tid, cb1 = tid + 256;
    const ushort_t* Bg0 = WeaT + (size_t)(n0 + (cb0 >> 2)) * ENC_ + (cb0 & 3) * 8;
    const ushort_t* Bg1 = WeaT + (size_t)(n0 + (cb1 >> 2)) * ENC_ + (cb1 & 3) * 8;
    const int aoA  = arA * 40 + akA;
    const int aoB0 = (cb0 >> 2) * 40 + (cb0 & 3) * 8;
    const int aoB1 = (cb1 >> 2) * 40 + (cb1 & 3) * 8;

    const int wn = wave * 32;
    f32x4 acc[4][2] = {};

    {
        float4 v0 = *reinterpret_cast<const float4*>(Ag);
        float4 v1 = *reinterpret_cast<const float4*>(Ag + 4);
        uint4 pa;
        pa.x = f2bf2(v0.x, v0.y); pa.y = f2bf2(v0.z, v0.w);
        pa.z = f2bf2(v1.x, v1.y); pa.w = f2bf2(v1.z, v1.w);
        *reinterpret_cast<uint4*>(&As[0][aoA]) = pa;
        *reinterpret_cast<uint4*>(&Bs[0][aoB0]) = *reinterpret_cast<const uint4*>(Bg0);
        *reinterpret_cast<uint4*>(&Bs[0][aoB1]) = *reinterpret_cast<const uint4*>(Bg1);
    }
    __syncthreads();

    for (int it = 0; it < 64; ++it) {
        const int cur = it & 1;
        uint4 npa, npb0, npb1;
        const bool more = (it < 63);
        if (more) {
            const int k0 = (it + 1) * 32;
            float4 v0 = *reinterpret_cast<const float4*>(Ag + k0);
            float4 v1 = *reinterpret_cast<const float4*>(Ag + k0 + 4);
            npa.x = f2bf2(v0.x, v0.y); npa.y = f2bf2(v0.z, v0.w);
            npa.z = f2bf2(v1.x, v1.y); npa.w = f2bf2(v1.z, v1.w);
            npb0 = *reinterpret_cast<const uint4*>(Bg0 + k0);
            npb1 = *reinterpret_cast<const uint4*>(Bg1 + k0);
        }
        {
            bf16x8 af[4], bfr[2];
            const int arow = lane & 15;
            const int koff = (lane >> 4) * 8;
#pragma unroll
            for (int mt = 0; mt < 4; ++mt)
                af[mt] = *reinterpret_cast<const bf16x8*>(&As[cur][(arow + mt * 16) * 40 + koff]);
#pragma unroll
            for (int nt = 0; nt < 2; ++nt)
                bfr[nt] = *reinterpret_cast<const bf16x8*>(&Bs[cur][(wn + nt * 16 + arow) * 40 + koff]);
#pragma unroll
            for (int mt = 0; mt < 4; ++mt)
#pragma unroll
                for (int nt = 0; nt < 2; ++nt)
                    acc[mt][nt] = __builtin_amdgcn_mfma_f32_16x16x32_bf16(
                        af[mt], bfr[nt], acc[mt][nt], 0, 0, 0);
        }
        if (more) {
            const int nxt = cur ^ 1;
            *reinterpret_cast<uint4*>(&As[nxt][aoA]) = npa;
            *reinterpret_cast<uint4*>(&Bs[nxt][aoB0]) = npb0;
            *reinterpret_cast<uint4*>(&Bs[nxt][aoB1]) = npb1;
        }
        __syncthreads();
    }
    const int rbase = (lane >> 4) * 4;
    const int cbase = lane & 15;
#pragma unroll
    for (int nt = 0; nt < 2; ++nt) {
        int col = n0 + wn + nt * 16 + cbase;
        float be = bea[col];
#pragma unroll
        for (int mt = 0; mt < 4; ++mt) {
            int row = m0 + mt * 16 + rbase;
#pragma unroll
            for (int r = 0; r < 4; ++r)
                a1b[(size_t)(row + r) * 512 + col] = f2bf(acc[mt][nt][r] + be);
        }
    }
}

// ============ prepack Wz = [Wl ; Ul] (K=3072) GATE-INTERLEAVED cols: n' = l*4 + g ============
__global__ void k_packWz(const float* __restrict__ Wl, const float* __restrict__ Ul,
                         ushort_t* __restrict__ Wz)
{
    const unsigned tidg = blockIdx.x * 256 + threadIdx.x;    // 786432 total, exact
    const int l = tidg & 63;
    const unsigned rem = tidg >> 6;
    const int kt = rem % 96;
    const int nt = rem / 96;
    const int k = kt * 32 + ((l >> 4) << 3);
    const int np = nt * 16 + (l & 15);          // packed col
    const int n = (np & 3) * 512 + (np >> 2);   // original col: gate (np&3), unit (np>>2)
    float v[8];
#pragma unroll
    for (int j = 0; j < 8; ++j) {
        int kr = k + j;
        v[j] = (kr < 2560) ? Wl[(size_t)kr * 2048 + n] : Ul[(size_t)(kr - 2560) * 2048 + n];
    }
    uint4 o;
    o.x = f2bf2(v[0], v[1]); o.y = f2bf2(v[2], v[3]);
    o.z = f2bf2(v[4], v[5]); o.w = f2bf2(v[6], v[7]);
    *reinterpret_cast<uint4*>(Wz + (size_t)tidg * 8) = o;
}

// ============ prepack Wc = [Wb | Wga | Wo | 0-pad] (K=512, N=12672) ============
__global__ void k_packWc(const float* __restrict__ Wb, const float* __restrict__ Wga,
                         const float* __restrict__ Wo, ushort_t* __restrict__ Wc)
{
    const unsigned tidg = blockIdx.x * 256 + threadIdx.x;    // 811008 total, exact
    const int l = tidg & 63;
    const int kt = (tidg >> 6) & 15;
    const int nt = tidg >> 10;
    const int k = kt * 32 + ((l >> 4) << 3);
    const int n = nt * 16 + (l & 15);
    float v[8];
#pragma unroll
    for (int j = 0; j < 8; ++j) {
        int kr = k + j;
        float x;
        if (n < 2048)            x = Wb[(size_t)kr * 2048 + n];
        else if (n < 2560)       x = Wga[(size_t)kr * 512 + (n - 2048)];
        else if (n < 2560 + V_)  x = Wo[(size_t)kr * V_ + (n - 2560)];
        else                     x = 0.f;
        v[j] = x;
    }
    uint4 o;
    o.x = f2bf2(v[0], v[1]); o.y = f2bf2(v[2], v[3]);
    o.z = f2bf2(v[4], v[5]); o.w = f2bf2(v[6], v[7]);
    *reinterpret_cast<uint4*>(Wc + (size_t)tidg * 8) = o;
}

// ============ GEMM2-lite (standalone, prologue step-0 prep only) ============
__global__ __launch_bounds__(256) void k_cmfma_lite(
    const ushort_t* __restrict__ cB, const ushort_t* __restrict__ WcP,
    const float* __restrict__ bb, const float* __restrict__ bga,
    int tnext, const int* __restrict__ seqs, const float* __restrict__ emb,
    const int* __restrict__ ord,
    float* __restrict__ beta, float* __restrict__ a2s, ushort_t* __restrict__ XB_out)
{
    const int bid = blockIdx.x, tid = threadIdx.x;
    if (bid >= 20) {
        const int g = (bid - 20) * 256 + tid;    // 0..511
        const int b = g >> 4, j0 = (g & 15) * 32;
        const int tok = seqs[ord[b] * T_ + tnext];
        const float4* src = reinterpret_cast<const float4*>(emb + (size_t)tok * E_ + j0);
        uint4* dst = reinterpret_cast<uint4*>(XB_out + (size_t)b * XW_ + j0);
#pragma unroll
        for (int q = 0; q < 4; ++q) {
            float4 v0 = src[2 * q], v1 = src[2 * q + 1];
            uint4 o;
            o.x = f2bf2(v0.x, v0.y); o.y = f2bf2(v0.z, v0.w);
            o.z = f2bf2(v1.x, v1.y); o.w = f2bf2(v1.z, v1.w);
            dst[q] = o;
        }
        return;
    }
    const int lane = tid & 63, w = tid >> 6;
    const int nt0 = bid * 8 + w * 2;
    const int ar = lane & 15, ak = (lane >> 4) * 8;
    const ushort_t* A0 = cB + ar * 512 + ak;
    const ushort_t* Bp = WcP + (size_t)nt0 * 8192 + lane * 8;
    f32x4 acc[2][2] = {};
    for (int kt = 0; kt < 16; ++kt) {
        bf16x8 a0 = *reinterpret_cast<const bf16x8*>(A0 + kt * 32);
        bf16x8 a1 = *reinterpret_cast<const bf16x8*>(A0 + 16 * 512 + kt * 32);
        bf16x8 b0 = *reinterpret_cast<const bf16x8*>(Bp + kt * 512);
        bf16x8 b1 = *reinterpret_cast<const bf16x8*>(Bp + 8192 + kt * 512);
        acc[0][0] = __builtin_amdgcn_mfma_f32_16x16x32_bf16(a0, b0, acc[0][0], 0, 0, 0);
        acc[0][1] = __builtin_amdgcn_mfma_f32_16x16x32_bf16(a0, b1, acc[0][1], 0, 0, 0);
        acc[1][0] = __builtin_amdgcn_mfma_f32_16x16x32_bf16(a1, b0, acc[1][0], 0, 0, 0);
        acc[1][1] = __builtin_amdgcn_mfma_f32_16x16x32_bf16(a1, b1, acc[1][1], 0, 0, 0);
    }
    const int r0 = (lane >> 4) * 4, cb2 = lane & 15;
#pragma unroll
    for (int nti = 0; nti < 2; ++nti) {
        const int n = (nt0 + nti) * 16 + cb2;
#pragma unroll
        for (int mt = 0; mt < 2; ++mt) {
#pragma unroll
            for (int r = 0; r < 4; ++r) {
                const int brow = mt * 16 + r0 + r;
                float v = acc[mt][nti][r];
                if (n < 2048) {
                    beta[brow * 2048 + n] = 1.f / (1.f + expf(-(v + bb[n])));
                } else {
                    a2s[brow * 512 + (n - 2048)] = v + bga[n - 2048];
                }
            }
        }
    }
}

// ============ PERSISTENT decode loop: 128 blocks, cooperative grid sync ============
// phase1 e (128 units) -> phase2 awex (128) -> phase3 zgates (128) -> phase4 cmfma_lite (22)
__global__ __launch_bounds__(256) void k_loop(
    const float* __restrict__ Wfa, const float* __restrict__ bfa,
    const ushort_t* __restrict__ a1b, const float* __restrict__ enc,
    const int* __restrict__ ord, const int* __restrict__ slen,
    float* __restrict__ eshW, float* __restrict__ a2s,
    float* __restrict__ beta, float* __restrict__ out_alpha,
    ushort_t* __restrict__ XB0, ushort_t* __restrict__ XB1,
    const ushort_t* __restrict__ WzP, const float* __restrict__ bl,
    float* __restrict__ cbuf, ushort_t* __restrict__ cBall,
    const ushort_t* __restrict__ WcP, const float* __restrict__ bb,
    const float* __restrict__ bga, const int* __restrict__ seqs,
    const float* __restrict__ emb)
{
    cg::grid_group grid = cg::this_grid();
    __shared__ float shbuf[2048];      // 8KB, reused across phases
    const int bid = blockIdx.x, tid = threadIdx.x;
    const int wave = tid >> 6, lane = tid & 63;

    for (int t = 0; t < STEPS; ++t) {
        ushort_t* xb_cur = (t & 1) ? XB1 : XB0;
        ushort_t* xb_nxt = (t & 1) ? XB0 : XB1;
        float* c_in  = cbuf + (t & 1) * (B_ * L_);
        float* c_out = cbuf + ((t + 1) & 1) * (B_ * L_);
        ushort_t* cB_slot = cBall + (size_t)t * (B_ * L_);

        // ===== phase 1: e (b = bid>>2, pc = bid&3) =====
        {
            float* a2sh = shbuf;
            float* wfsh = shbuf + 512;
            const int b = bid >> 2, pc = bid & 3;
            a2sh[tid] = a2s[b * 512 + tid];   a2sh[tid + 256] = a2s[b * 512 + 256 + tid];
            wfsh[tid] = Wfa[tid];             wfsh[tid + 256] = Wfa[256 + tid];
            __syncthreads();
            const int grp = lane >> 4, sub = lane & 15;
            float4 a2r[4][2], wfr[4][2];
#pragma unroll
            for (int blk = 0; blk < 4; ++blk)
#pragma unroll
                for (int j = 0; j < 2; ++j) {
                    int d = blk * 128 + sub * 8 + j * 4;
                    a2r[blk][j] = *reinterpret_cast<const float4*>(&a2sh[d]);
                    wfr[blk][j] = *reinterpret_cast<const float4*>(&wfsh[d]);
                }
            const float bf0 = bfa[0];
            const int p0 = pc * 49;
#pragma unroll
            for (int pass = 0; pass < 4; ++pass) {
                const int pl = pass * 16 + wave * 4 + grp;
                const bool valid = pl < 49;
                const int p = p0 + (valid ? pl : 0);
                const ushort_t* arow = a1b + ((size_t)b * P_ + p) * 512;
                float s = 0.f;
#pragma unroll
                for (int blk = 0; blk < 4; ++blk) {
                    uint4 raw = *reinterpret_cast<const uint4*>(arow + blk * 128 + sub * 8);
                    float4 av = a2r[blk][0], wv = wfr[blk][0];
                    float v;
                    v = bfu_lo(raw.x) + av.x; v = v > 0.f ? v : 0.f; s += v * wv.x;
                    v = bfu_hi(raw.x) + av.y; v = v > 0.f ? v : 0.f; s += v * wv.y;
                    v = bfu_lo(raw.y) + av.z; v = v > 0.f ? v : 0.f; s += v * wv.z;
                    v = bfu_hi(raw.y) + av.w; v = v > 0.f ? v : 0.f; s += v * wv.w;
                    av = a2r[blk][1]; wv = wfr[blk][1];
                    v = bfu_lo(raw.z) + av.x; v = v > 0.f ? v : 0.f; s += v * wv.x;
                    v = bfu_hi(raw.z) + av.y; v = v > 0.f ? v : 0.f; s += v * wv.y;
                    v = bfu_lo(raw.w) + av.z; v = v > 0.f ? v : 0.f; s += v * wv.z;
                    v = bfu_hi(raw.w) + av.w; v = v > 0.f ? v : 0.f; s += v * wv.w;
                }
                s += __shfl_xor(s, 1, 64);
                s += __shfl_xor(s, 2, 64);
                s += __shfl_xor(s, 4, 64);
                s += __shfl_xor(s, 8, 64);
                if (sub == 0 && valid) eshW[b * 256 + p0 + pl] = s + bf0;
            }
        }
        grid.sync();

        // ===== phase 2: softmax + awe + beta-gate + x-write (b = bid>>2, ec = bid&3) =====
        {
            float* red  = shbuf;
            float* alsh = shbuf + 256;
            const int b = bid >> 2, ec = bid & 3;

            float v = (tid < P_) ? eshW[b * 256 + tid] : -1e30f;
            red[tid] = v; __syncthreads();
            for (int s2 = 128; s2 > 0; s2 >>= 1) {
                if (tid < s2) red[tid] = fmaxf(red[tid], red[tid + s2]);
                __syncthreads();
            }
            float mx = red[0]; __syncthreads();
            float ex = (tid < P_) ? expf(v - mx) : 0.f;
            red[tid] = ex; __syncthreads();
            for (int s2 = 128; s2 > 0; s2 >>= 1) {
                if (tid < s2) red[tid] += red[tid + s2];
                __syncthreads();
            }
            float inv = 1.0f / red[0];
            float al = ex * inv;
            if (tid < P_) alsh[tid] = al;
            if (ec == 0 && tid < P_) {
                float mf = (slen[b] > t) ? 1.f : 0.f;
                out_alpha[((size_t)b * STEPS + t) * P_ + tid] = al * mf;
            }
            __syncthreads();

            const int e0 = ec * 512 + tid * 2;
            const float* ep = enc + (size_t)ord[b] * (P_ * ENC_) + e0;
            float s0 = 0.f, s1 = 0.f;
            for (int p = 0; p < P_; ++p) {
                float2 u = *reinterpret_cast<const float2*>(ep + (size_t)p * ENC_);
                float ap = alsh[p];
                s0 += ap * u.x; s1 += ap * u.y;
            }
            float2 bt = *reinterpret_cast<const float2*>(&beta[b * 2048 + e0]);
            unsigned pk = f2bf2(s0 * bt.x, s1 * bt.y);
            *reinterpret_cast<unsigned*>(xb_cur + (size_t)b * XW_ + 512 + e0) = pk;
        }
        grid.sync();

        // ===== phase 3: z-GEMM + gates (nt = bid) =====
        {
            float (*zsh)[32][16] = reinterpret_cast<float(*)[32][16]>(shbuf);
            const int nt = bid;
            const int kt0 = wave * 24;
            const int ar = lane & 15, ak = (lane >> 4) * 8;
            const ushort_t* A0 = xb_cur + (size_t)ar * XW_ + kt0 * 32 + ak;
            const ushort_t* Bp = WzP + ((size_t)nt * 96 + kt0) * 512 + lane * 8;
            f32x4 acc0 = {}, acc1 = {};
            for (int kt = 0; kt < 24; ++kt) {
                bf16x8 a0 = *reinterpret_cast<const bf16x8*>(A0 + kt * 32);
                bf16x8 a1 = *reinterpret_cast<const bf16x8*>(A0 + 16 * XW_ + kt * 32);
                bf16x8 bf = *reinterpret_cast<const bf16x8*>(Bp + kt * 512);
                acc0 = __builtin_amdgcn_mfma_f32_16x16x32_bf16(a0, bf, acc0, 0, 0, 0);
                acc1 = __builtin_amdgcn_mfma_f32_16x16x32_bf16(a1, bf, acc1, 0, 0, 0);
            }
            const int col = lane & 15, r0 = (lane >> 4) * 4;
#pragma unroll
            for (int r = 0; r < 4; ++r) {
                zsh[wave][r0 + r][col] = acc0[r];
                zsh[wave][16 + r0 + r][col] = acc1[r];
            }
            __syncthreads();
            if (tid < 128) {
                const int b = tid >> 2, li = tid & 3;
                const int l = nt * 4 + li;
                float z[4];
#pragma unroll
                for (int g = 0; g < 4; ++g) {
                    const int c = li * 4 + g;
                    z[g] = zsh[0][b][c] + zsh[1][b][c] + zsh[2][b][c] + zsh[3][b][c]
                         + bl[g * 512 + l];
                }
                float si = 1.f / (1.f + expf(-z[0]));
                float sf = 1.f / (1.f + expf(-z[1]));
                float gg = tanhf(z[2]);
                float so = 1.f / (1.f + expf(-z[3]));
                float cn = sf * c_in[b * 512 + l] + si * gg;
                float hn = so * tanhf(cn);
                float mf = (slen[b] > t) ? 1.f : 0.f;
                cn *= mf; hn *= mf;
                c_out[b * 512 + l] = cn;
                cB_slot[b * 512 + l] = f2bf(cn);
                xb_nxt[(size_t)b * XW_ + 2560 + l] = f2bf(hn);
            }
        }
        grid.sync();

        // ===== phase 4: cB @ [Wb|Wga] -> beta,a2s; emb gather (bid < 22) =====
        if (bid < 22) {
            if (bid >= 20) {
                const int g = (bid - 20) * 256 + tid;    // 0..511
                const int b = g >> 4, j0 = (g & 15) * 32;
                const int tok = seqs[ord[b] * T_ + (t + 1)];
                const float4* src = reinterpret_cast<const float4*>(emb + (size_t)tok * E_ + j0);
                uint4* dst = reinterpret_cast<uint4*>(xb_nxt + (size_t)b * XW_ + j0);
#pragma unroll
                for (int q = 0; q < 4; ++q) {
                    float4 v0 = src[2 * q], v1 = src[2 * q + 1];
                    uint4 o;
                    o.x = f2bf2(v0.x, v0.y); o.y = f2bf2(v0.z, v0.w);
                    o.z = f2bf2(v1.x, v1.y); o.w = f2bf2(v1.z, v1.w);
                    dst[q] = o;
                }
            } else {
                const int nt0 = bid * 8 + wave * 2;
                const int ar = lane & 15, ak = (lane >> 4) * 8;
                const ushort_t* A0 = cB_slot + ar * 512 + ak;
                const ushort_t* Bp = WcP + (size_t)nt0 * 8192 + lane * 8;
                f32x4 acc[2][2] = {};
                for (int kt = 0; kt < 16; ++kt) {
                    bf16x8 a0 = *reinterpret_cast<const bf16x8*>(A0 + kt * 32);
                    bf16x8 a1 = *reinterpret_cast<const bf16x8*>(A0 + 16 * 512 + kt * 32);
                    bf16x8 b0 = *reinterpret_cast<const bf16x8*>(Bp + kt * 512);
                    bf16x8 b1 = *reinterpret_cast<const bf16x8*>(Bp + 8192 + kt * 512);
                    acc[0][0] = __builtin_amdgcn_mfma_f32_16x16x32_bf16(a0, b0, acc[0][0], 0, 0, 0);
                    acc[0][1] = __builtin_amdgcn_mfma_f32_16x16x32_bf16(a0, b1, acc[0][1], 0, 0, 0);
                    acc[1][0] = __builtin_amdgcn_mfma_f32_16x16x32_bf16(a1, b0, acc[1][0], 0, 0, 0);
                    acc[1][1] = __builtin_amdgcn_mfma_f32_16x16x32_bf16(a1, b1, acc[1][1], 0, 0, 0);
                }
                const int r0 = (lane >> 4) * 4, cb2 = lane & 15;
#pragma unroll
                for (int nti = 0; nti < 2; ++nti) {
                    const int n = (nt0 + nti) * 16 + cb2;
#pragma unroll
                    for (int mt = 0; mt < 2; ++mt) {
#pragma unroll
                        for (int r = 0; r < 4; ++r) {
                            const int brow = mt * 16 + r0 + r;
                            float v = acc[mt][nti][r];
                            if (n < 2048) {
                                beta[brow * 2048 + n] = 1.f / (1.f + expf(-(v + bb[n])));
                            } else {
                                a2s[brow * 512 + (n - 2048)] = v + bga[n - 2048];
                            }
                        }
                    }
                }
            }
        }
        grid.sync();
    }
}

// ============ batched pred GEMM: cBall(640x512) @ WoPack(512x10000) + bo, masked ============
__global__ __launch_bounds__(256) void k_pred(
    const ushort_t* __restrict__ cBall, const ushort_t* __restrict__ WcP,
    const float* __restrict__ bo, const int* __restrict__ slen,
    float* __restrict__ out_pred)
{
    const int tid = threadIdx.x, lane = tid & 63, w = tid >> 6;
    const int n0 = blockIdx.x * 128;
    const int m0 = blockIdx.y * 128;
    const int wm = (w >> 1) * 64, wn = (w & 1) * 64;
    const int ar = lane & 15, ak = (lane >> 4) * 8;
    const int ntb = (2560 + n0 + wn) >> 4;
    f32x4 acc[4][4] = {};
    for (int kt = 0; kt < 16; ++kt) {
        bf16x8 af[4], bfr[4];
#pragma unroll
        for (int mt = 0; mt < 4; ++mt)
            af[mt] = *reinterpret_cast<const bf16x8*>(
                cBall + (size_t)(m0 + wm + mt * 16 + ar) * 512 + kt * 32 + ak);
#pragma unroll
        for (int nt = 0; nt < 4; ++nt)
            bfr[nt] = *reinterpret_cast<const bf16x8*>(
                WcP + ((size_t)(ntb + nt) * 16 + kt) * 512 + lane * 8);
#pragma unroll
        for (int mt = 0; mt < 4; ++mt)
#pragma unroll
            for (int nt = 0; nt < 4; ++nt)
                acc[mt][nt] = __builtin_amdgcn_mfma_f32_16x16x32_bf16(
                    af[mt], bfr[nt], acc[mt][nt], 0, 0, 0);
    }
    const int r0 = (lane >> 4) * 4, cb = lane & 15;
#pragma unroll
    for (int nt = 0; nt < 4; ++nt) {
        const int n = n0 + wn + nt * 16 + cb;
        if (n < V_) {
            const float bv = bo[n];
#pragma unroll
            for (int mt = 0; mt < 4; ++mt) {
#pragma unroll
                for (int r = 0; r < 4; ++r) {
                    const int m = m0 + wm + mt * 16 + r0 + r;     // m = t*32 + b
                    const int tt = m >> 5, bb_ = m & 31;
                    const float mf = (slen[bb_] > tt) ? 1.f : 0.f;
                    out_pred[((size_t)bb_ * STEPS + tt) * V_ + n] =
                        (acc[mt][nt][r] + bv) * mf;
                }
            }
        }
    }
}

extern "C" void kernel_launch(void* const* d_in, const int* in_sizes, int n_in,
                              void* d_out, int out_size, void* d_ws, size_t ws_size,
                              hipStream_t stream)
{
    const float* enc  = (const float*)d_in[0];
    const int*   seqs = (const int*)  d_in[1];
    const float* emb  = (const float*)d_in[2];
    const float* Wea  = (const float*)d_in[3];
    const float* bea  = (const float*)d_in[4];
    const float* Wga  = (const float*)d_in[5];
    const float* bga  = (const float*)d_in[6];
    const float* Wfa  = (const float*)d_in[7];
    const float* bfa  = (const float*)d_in[8];
    const float* Wl   = (const float*)d_in[9];
    const float* Ul   = (const float*)d_in[10];
    const float* bl   = (const float*)d_in[11];
    const float* Wim  = (const float*)d_in[12];
    const float* bim  = (const float*)d_in[13];
    const float* Wic  = (const float*)d_in[14];
    const float* bic  = (const float*)d_in[15];
    const float* Wb   = (const float*)d_in[16];
    const float* bb   = (const float*)d_in[17];
    const float* Wo   = (const float*)d_in[18];
    const float* bo   = (const float*)d_in[19];

    float* out = (float*)d_out;
    float* ws  = (float*)d_ws;
    int* ord  = (int*)(ws + WS_ORD);
    int* slen = (int*)(ws + WS_SLEN);
    ushort_t* cB0   = (ushort_t*)(ws + WS_CB0);
    ushort_t* cBall = (ushort_t*)(ws + WS_CBALL);
    ushort_t* XB0   = (ushort_t*)(ws + WS_XB);
    ushort_t* XB1   = (ushort_t*)(ws + WS_XB) + (size_t)B_ * XW_;
    ushort_t* a1b   = (ushort_t*)(ws + WS_A1B);
    ushort_t* WzP   = (ushort_t*)(ws + WS_WZP);
    ushort_t* WcP   = (ushort_t*)(ws + WS_WCP);
    ushort_t* WeaT  = (ushort_t*)(ws + WS_WEAT);
    float* a2s  = ws + WS_A2S;
    float* beta = ws + WS_BETA;
    float* eshW = ws + WS_ESH;
    float* cbuf = ws + WS_CBUF;
    float* out_alpha = out + OUT_ALPHA;

    // ---- prologue ----
    k_order<<<1, 64, 0, stream>>>(seqs, ord, slen, out + OUT_ORDER);
    k_mean<<<256, 256, 0, stream>>>(enc, ord, ws + WS_MEAN);
    sg_partial<<<dim3(2, 16, 2), 256, 0, stream>>>(ws + WS_MEAN, Wim, ws + WS_PH, 2048, 512, 128, 0);
    sg_partial<<<dim3(2, 16, 2), 256, 0, stream>>>(ws + WS_MEAN, Wic, ws + WS_PH, 2048, 512, 128, 16);
    k_h0c0<<<128, 256, 0, stream>>>(ws + WS_PH, bim, bic, cbuf, cB0, XB0);
    k_castWT<<<4096, 256, 0, stream>>>(Wea, WeaT);
    k_a1_mfma<<<dim3(98, 4), 256, 0, stream>>>(enc, WeaT, bea, ord, a1b);
    k_packWz<<<3072, 256, 0, stream>>>(Wl, Ul, WzP);      // overwrites MEAN/PH (dead)
    k_packWc<<<3168, 256, 0, stream>>>(Wb, Wga, Wo, WcP); // overwrites WeaT (dead)
    // prep for step 0: beta, a2s, emb(0) -> XB0 from c0
    k_cmfma_lite<<<22, 256, 0, stream>>>(cB0, WcP, bb, bga, 0, seqs, emb, ord,
                                         beta, a2s, XB0);

    // ---- persistent cooperative decode loop (all 20 steps, 1 dispatch) ----
    {
        void* kargs[] = {
            (void*)&Wfa, (void*)&bfa, (void*)&a1b, (void*)&enc,
            (void*)&ord, (void*)&slen, (void*)&eshW, (void*)&a2s,
            (void*)&beta, (void*)&out_alpha, (void*)&XB0, (void*)&XB1,
            (void*)&WzP, (void*)&bl, (void*)&cbuf, (void*)&cBall,
            (void*)&WcP, (void*)&bb, (void*)&bga, (void*)&seqs, (void*)&emb
        };
        hipLaunchCooperativeKernel((void*)k_loop, dim3(128), dim3(256),
                                   kargs, 0, stream);
    }

    // ---- batched prediction GEMM ----
    k_pred<<<dim3(79, 5), 256, 0, stream>>>(cBall, WcP, bo, slen, out + OUT_PRED);
}

// Round 6
// 1146.846 us; speedup vs baseline: 2.4396x; 2.4396x over previous
//
#include <hip/hip_runtime.h>
#include <math.h>

#define B_    32
#define T_    21
#define STEPS 20
#define V_    10000
#define E_    512
#define A_    512
#define L_    512
#define P_    196
#define ENC_  2048
#define XW_   3072   // bf16 X' row: [emb(512) | awe*beta(2048) | h(512)]

// ---- workspace layout (float offsets), total 8,908,864 fl = 35.6 MB ----
#define WS_ORD    0
#define WS_SLEN   32
#define WS_CBUF   64        // 2*16384 fp32 c double-buffer
#define WS_CB0    32832     // bf16 32*512 (c0, prologue)      -> 4096 fl
#define WS_CBALL  36928     // bf16 20*32*512 (c per step)     -> 163840 fl
#define WS_XB     200768    // bf16 2 x 32*3072 (double-buffered) -> 98304 fl
#define WS_A2S    299072    // 32*512
#define WS_BETA   315456    // 32*2048
#define WS_ESH    380992    // 32*256 (unused now, kept for layout stability)
#define WS_A1B    389184    // bf16 6272*512 -> 1605632 fl
#define WS_WZP    1994816   // bf16 128nt*96kt*64*8 -> 3145728 fl
#define WS_WCP    5140544   // bf16 792nt*16kt*64*8 -> 3244032 fl
#define WS_WEAT   8384576   // bf16 512*2048 -> 524288 fl (own region; end 8908864)
// prologue-only aliases (stream-ordered: dead before k_packAll writes WzP):
#define WS_MEAN   (WS_WZP)           // 65536 fl; dead after sg_both
#define WS_PH     (WS_WZP + 65536)   // 524288 fl; dead after k_h0c0

// ---- output layout (float offsets) ----
#define OUT_PRED  0
#define OUT_ALPHA 6400000
#define OUT_ORDER 6525440

typedef __attribute__((ext_vector_type(8))) short bf16x8;
typedef __attribute__((ext_vector_type(4))) float f32x4;
typedef unsigned short ushort_t;

__device__ inline unsigned f2bf2(float lo, float hi) {
    unsigned a = __float_as_uint(lo), b = __float_as_uint(hi);
    a = (a + 0x7FFFu + ((a >> 16) & 1u)) >> 16;
    b = (b + 0x7FFFu + ((b >> 16) & 1u)) >> 16;
    return a | (b << 16);
}
__device__ inline ushort_t f2bf(float f) {
    unsigned u = __float_as_uint(f);
    return (ushort_t)((u + 0x7FFFu + ((u >> 16) & 1u)) >> 16);
}
__device__ inline float bfu_lo(unsigned u) { return __uint_as_float(u << 16); }
__device__ inline float bfu_hi(unsigned u) { return __uint_as_float(u & 0xFFFF0000u); }

// ============ order / lengths ============
__global__ void k_order(const int* __restrict__ seqs, int* __restrict__ ord,
                        int* __restrict__ slen, float* __restrict__ out_ord)
{
    __shared__ int len[B_];
    int i = threadIdx.x;
    if (i < B_) {
        int c = 0;
        for (int t = 0; t < T_; ++t) c += (seqs[i * T_ + t] != 0) ? 1 : 0;
        len[i] = c;
    }
    __syncthreads();
    if (i < B_) {
        int li = len[i], r = 0;
        for (int j = 0; j < B_; ++j) {
            int lj = len[j];
            if (lj > li || (lj == li && j < i)) ++r;
        }
        ord[r] = i; slen[r] = li - 1; out_ord[r] = (float)i;
    }
}

// ============ mean-pool encoder (sorted) ============
__global__ void k_mean(const float* __restrict__ enc, const int* __restrict__ ord,
                       float* __restrict__ mean)
{
    int tid = blockIdx.x * 256 + threadIdx.x;
    int b = tid >> 11, e = tid & 2047;
    const float* row = enc + (size_t)ord[b] * (P_ * ENC_) + e;
    float s = 0.f;
    for (int p = 0; p < P_; ++p) s += row[(size_t)p * ENC_];
    mean[tid] = s * (1.0f / 196.0f);
}

// ============ prologue skinny GEMM partials for h0 AND c0 in one dispatch ============
// grid (2, 16, 4): z = bh | (which<<1); which 0 -> Wim (slots 0..15), 1 -> Wic (16..31)
__global__ void sg_both(const float* __restrict__ X, const float* __restrict__ Wim,
                        const float* __restrict__ Wic, float* __restrict__ part)
{
    const int n = blockIdx.x * 256 + threadIdx.x;
    const int c = blockIdx.y;
    const int bh = blockIdx.z & 1;
    const int which = blockIdx.z >> 1;
    const float* W = which ? Wic : Wim;
    const int chunk_ofs = which * 16;
    const int k0 = c * 128;
    const int k1 = k0 + 128;
    float acc[16];
#pragma unroll
    for (int b = 0; b < 16; ++b) acc[b] = 0.f;
    const float* Xb = X + (size_t)(bh * 16) * 2048;
    for (int k = k0; k < k1; k += 4) {
        float w0 = W[(size_t)(k + 0) * 512 + n];
        float w1 = W[(size_t)(k + 1) * 512 + n];
        float w2 = W[(size_t)(k + 2) * 512 + n];
        float w3 = W[(size_t)(k + 3) * 512 + n];
#pragma unroll
        for (int b = 0; b < 16; ++b) {
            const float4 xv = *reinterpret_cast<const float4*>(&Xb[(size_t)b * 2048 + k]);
            acc[b] += xv.x * w0 + xv.y * w1 + xv.z * w2 + xv.w * w3;
        }
    }
    float* po = part + (size_t)(chunk_ofs + c) * (B_ * 512) + (size_t)(bh * 16) * 512;
#pragma unroll
    for (int b = 0; b < 16; ++b) po[(size_t)b * 512 + n] = acc[b];
}

// ============ h0/c0 combine: c0 fp32 + cB0 bf16 + h0 into XB0 h-section ============
__global__ void k_h0c0(const float* __restrict__ ph, const float* __restrict__ bim,
                       const float* __restrict__ bic, float* __restrict__ c0,
                       ushort_t* __restrict__ cB0, ushort_t* __restrict__ XB0)
{
    int tid = blockIdx.x * 256 + threadIdx.x;
    int half = tid >> 14;
    int idx = tid & 16383;
    int l = idx & 511, b = idx >> 9;
    int cofs = half ? 16 : 0;
    float s = 0.f;
    for (int c = 0; c < 16; ++c) s += ph[(size_t)(cofs + c) * (B_ * 512) + idx];
    if (half) {
        float cv = s + bic[l];
        c0[idx] = cv;
        cB0[idx] = f2bf(cv);
    } else {
        XB0[(size_t)b * XW_ + 2560 + l] = f2bf(s + bim[l]);
    }
}

// ============ all weight packing in one dispatch ============
// bids 0..4095: Wea->WeaT | 4096..7167: packWz | 7168..10335: packWc
__global__ void k_packAll(const float* __restrict__ Wea, const float* __restrict__ Wl,
                          const float* __restrict__ Ul, const float* __restrict__ Wb,
                          const float* __restrict__ Wga, const float* __restrict__ Wo,
                          ushort_t* __restrict__ WT, ushort_t* __restrict__ Wz,
                          ushort_t* __restrict__ Wc)
{
    const int bid = blockIdx.x;
    if (bid < 4096) {
        int tid = bid * 256 + threadIdx.x;
        int n = tid >> 11, k = tid & 2047;
        WT[tid] = f2bf(Wea[(size_t)k * 512 + n]);
    } else if (bid < 7168) {
        const unsigned tidg = (unsigned)(bid - 4096) * 256 + threadIdx.x;  // < 786432
        const int l = tidg & 63;
        const unsigned rem = tidg >> 6;
        const int kt = rem % 96;
        const int nt = rem / 96;
        const int k = kt * 32 + ((l >> 4) << 3);
        const int np = nt * 16 + (l & 15);          // packed col
        const int n = (np & 3) * 512 + (np >> 2);   // gate-interleaved original col
        float v[8];
#pragma unroll
        for (int j = 0; j < 8; ++j) {
            int kr = k + j;
            v[j] = (kr < 2560) ? Wl[(size_t)kr * 2048 + n] : Ul[(size_t)(kr - 2560) * 2048 + n];
        }
        uint4 o;
        o.x = f2bf2(v[0], v[1]); o.y = f2bf2(v[2], v[3]);
        o.z = f2bf2(v[4], v[5]); o.w = f2bf2(v[6], v[7]);
        *reinterpret_cast<uint4*>(Wz + (size_t)tidg * 8) = o;
    } else {
        const unsigned tidg = (unsigned)(bid - 7168) * 256 + threadIdx.x;  // < 811008
        const int l = tidg & 63;
        const int kt = (tidg >> 6) & 15;
        const int nt = tidg >> 10;
        const int k = kt * 32 + ((l >> 4) << 3);
        const int n = nt * 16 + (l & 15);
        float v[8];
#pragma unroll
        for (int j = 0; j < 8; ++j) {
            int kr = k + j;
            float x;
            if (n < 2048)            x = Wb[(size_t)kr * 2048 + n];
            else if (n < 2560)       x = Wga[(size_t)kr * 512 + (n - 2048)];
            else if (n < 2560 + V_)  x = Wo[(size_t)kr * V_ + (n - 2560)];
            else                     x = 0.f;
            v[j] = x;
        }
        uint4 o;
        o.x = f2bf2(v[0], v[1]); o.y = f2bf2(v[2], v[3]);
        o.z = f2bf2(v[4], v[5]); o.w = f2bf2(v[6], v[7]);
        *reinterpret_cast<uint4*>(Wc + (size_t)tidg * 8) = o;
    }
}

// ============ a1 MFMA, 64-row M-tiles (grid 98x4 = 392 blocks) — r4 verified ============
__global__ __launch_bounds__(256) void k_a1_mfma(
    const float* __restrict__ enc, const ushort_t* __restrict__ WeaT,
    const float* __restrict__ bea, const int* __restrict__ ord,
    ushort_t* __restrict__ a1b)
{
    __shared__ ushort_t As[2][64 * 40];
    __shared__ ushort_t Bs[2][128 * 40];
    const int tid = threadIdx.x;
    const int lane = tid & 63, wave = tid >> 6;
    const int m0 = blockIdx.x * 64;
    const int n0 = blockIdx.y * 128;

    const int arA = tid >> 2, akA = (tid & 3) * 8;
    const int gA = m0 + arA;
    const float* Ag = enc + ((size_t)ord[gA / P_] * P_ + (gA % P_)) * ENC_ + akA;
    const int cb0 = tid, cb1 = tid + 256;
    const ushort_t* Bg0 = WeaT + (size_t)(n0 + (cb0 >> 2)) * ENC_ + (cb0 & 3) * 8;
    const ushort_t* Bg1 = WeaT + (size_t)(n0 + (cb1 >> 2)) * ENC_ + (cb1 & 3) * 8;
    const int aoA  = arA * 40 + akA;
    const int aoB0 = (cb0 >> 2) * 40 + (cb0 & 3) * 8;
    const int aoB1 = (cb1 >> 2) * 40 + (cb1 & 3) * 8;

    const int wn = wave * 32;
    f32x4 acc[4][2] = {};

    {
        float4 v0 = *reinterpret_cast<const float4*>(Ag);
        float4 v1 = *reinterpret_cast<const float4*>(Ag + 4);
        uint4 pa;
        pa.x = f2bf2(v0.x, v0.y); pa.y = f2bf2(v0.z, v0.w);
        pa.z = f2bf2(v1.x, v1.y); pa.w = f2bf2(v1.z, v1.w);
        *reinterpret_cast<uint4*>(&As[0][aoA]) = pa;
        *reinterpret_cast<uint4*>(&Bs[0][aoB0]) = *reinterpret_cast<const uint4*>(Bg0);
        *reinterpret_cast<uint4*>(&Bs[0][aoB1]) = *reinterpret_cast<const uint4*>(Bg1);
    }
    __syncthreads();

    for (int it = 0; it < 64; ++it) {
        const int cur = it & 1;
        uint4 npa, npb0, npb1;
        const bool more = (it < 63);
        if (more) {
            const int k0 = (it + 1) * 32;
            float4 v0 = *reinterpret_cast<const float4*>(Ag + k0);
            float4 v1 = *reinterpret_cast<const float4*>(Ag + k0 + 4);
            npa.x = f2bf2(v0.x, v0.y); npa.y = f2bf2(v0.z, v0.w);
            npa.z = f2bf2(v1.x, v1.y); npa.w = f2bf2(v1.z, v1.w);
            npb0 = *reinterpret_cast<const uint4*>(Bg0 + k0);
            npb1 = *reinterpret_cast<const uint4*>(Bg1 + k0);
        }
        {
            bf16x8 af[4], bfr[2];
            const int arow = lane & 15;
            const int koff = (lane >> 4) * 8;
#pragma unroll
            for (int mt = 0; mt < 4; ++mt)
                af[mt] = *reinterpret_cast<const bf16x8*>(&As[cur][(arow + mt * 16) * 40 + koff]);
#pragma unroll
            for (int nt = 0; nt < 2; ++nt)
                bfr[nt] = *reinterpret_cast<const bf16x8*>(&Bs[cur][(wn + nt * 16 + arow) * 40 + koff]);
#pragma unroll
            for (int mt = 0; mt < 4; ++mt)
#pragma unroll
                for (int nt = 0; nt < 2; ++nt)
                    acc[mt][nt] = __builtin_amdgcn_mfma_f32_16x16x32_bf16(
                        af[mt], bfr[nt], acc[mt][nt], 0, 0, 0);
        }
        if (more) {
            const int nxt = cur ^ 1;
            *reinterpret_cast<uint4*>(&As[nxt][aoA]) = npa;
            *reinterpret_cast<uint4*>(&Bs[nxt][aoB0]) = npb0;
            *reinterpret_cast<uint4*>(&Bs[nxt][aoB1]) = npb1;
        }
        __syncthreads();
    }
    const int rbase = (lane >> 4) * 4;
    const int cbase = lane & 15;
#pragma unroll
    for (int nt = 0; nt < 2; ++nt) {
        int col = n0 + wn + nt * 16 + cbase;
        float be = bea[col];
#pragma unroll
        for (int mt = 0; mt < 4; ++mt) {
            int row = m0 + mt * 16 + rbase;
#pragma unroll
            for (int r = 0; r < 4; ++r)
                a1b[(size_t)(row + r) * 512 + col] = f2bf(acc[mt][nt][r] + be);
        }
    }
}

// ============ fused e + softmax + awe + beta-gate + x-write (+out_alpha): 128 blocks ============
// r2-verified kernel (passed at absmax 4.88e-4), verbatim.
__global__ __launch_bounds__(256, 1) void k_eawex(
    const float* __restrict__ a2s, const float* __restrict__ Wfa,
    const float* __restrict__ bfa, const ushort_t* __restrict__ a1b,
    const float* __restrict__ enc, const int* __restrict__ ord,
    const int* __restrict__ slen, int t, const float* __restrict__ beta,
    float* __restrict__ out_alpha, ushort_t* __restrict__ XB)
{
    __shared__ float a2sh[512];
    __shared__ float wfsh[512];
    __shared__ float esh[208];
    __shared__ float red[256];
    __shared__ float part[4][512];
    const int b = blockIdx.x >> 2, ec = blockIdx.x & 3;
    const int tid = threadIdx.x;
    const int wave = tid >> 6, lane = tid & 63;
    a2sh[tid] = a2s[b * 512 + tid];       a2sh[tid + 256] = a2s[b * 512 + 256 + tid];
    wfsh[tid] = Wfa[tid];                 wfsh[tid + 256] = Wfa[256 + tid];
    __syncthreads();

    const int grp = lane >> 4, sub = lane & 15;
    float4 a2r[4][2], wfr[4][2];
#pragma unroll
    for (int blk = 0; blk < 4; ++blk)
#pragma unroll
        for (int j = 0; j < 2; ++j) {
            int d = blk * 128 + sub * 8 + j * 4;
            a2r[blk][j] = *reinterpret_cast<const float4*>(&a2sh[d]);
            wfr[blk][j] = *reinterpret_cast<const float4*>(&wfsh[d]);
        }
    const float bf0 = bfa[0];
    // e for all 196 p-rows: 13 passes of 16 rows (one 16-lane group per row)
#pragma unroll
    for (int pass = 0; pass < 13; ++pass) {
        const int pl = pass * 16 + wave * 4 + grp;
        const bool valid = pl < P_;
        const int p = valid ? pl : 0;
        const ushort_t* arow = a1b + ((size_t)b * P_ + p) * 512;
        float s = 0.f;
#pragma unroll
        for (int blk = 0; blk < 4; ++blk) {
            uint4 raw = *reinterpret_cast<const uint4*>(arow + blk * 128 + sub * 8);
            float4 av = a2r[blk][0], wv = wfr[blk][0];
            float v;
            v = bfu_lo(raw.x) + av.x; v = v > 0.f ? v : 0.f; s += v * wv.x;
            v = bfu_hi(raw.x) + av.y; v = v > 0.f ? v : 0.f; s += v * wv.y;
            v = bfu_lo(raw.y) + av.z; v = v > 0.f ? v : 0.f; s += v * wv.z;
            v = bfu_hi(raw.y) + av.w; v = v > 0.f ? v : 0.f; s += v * wv.w;
            av = a2r[blk][1]; wv = wfr[blk][1];
            v = bfu_lo(raw.z) + av.x; v = v > 0.f ? v : 0.f; s += v * wv.x;
            v = bfu_hi(raw.z) + av.y; v = v > 0.f ? v : 0.f; s += v * wv.y;
            v = bfu_lo(raw.w) + av.z; v = v > 0.f ? v : 0.f; s += v * wv.z;
            v = bfu_hi(raw.w) + av.w; v = v > 0.f ? v : 0.f; s += v * wv.w;
        }
        s += __shfl_xor(s, 1, 64);
        s += __shfl_xor(s, 2, 64);
        s += __shfl_xor(s, 4, 64);
        s += __shfl_xor(s, 8, 64);
        if (sub == 0 && valid) esh[pl] = s + bf0;
    }
    __syncthreads();

    // softmax over esh[196]
    float v = (tid < P_) ? esh[tid] : -1e30f;
    red[tid] = v; __syncthreads();
    for (int s2 = 128; s2 > 0; s2 >>= 1) {
        if (tid < s2) red[tid] = fmaxf(red[tid], red[tid + s2]);
        __syncthreads();
    }
    float mx = red[0]; __syncthreads();
    float ex = (tid < P_) ? expf(v - mx) : 0.f;
    red[tid] = ex; __syncthreads();
    for (int s2 = 128; s2 > 0; s2 >>= 1) {
        if (tid < s2) red[tid] += red[tid + s2];
        __syncthreads();
    }
    float inv = 1.0f / red[0];
    float al = ex * inv;
    __syncthreads();
    if (tid < P_) esh[tid] = al;     // esh becomes alpha
    if (ec == 0 && tid < P_) {
        float mf = (slen[b] > t) ? 1.f : 0.f;
        out_alpha[((size_t)b * STEPS + t) * P_ + tid] = al * mf;
    }
    __syncthreads();

    // awe partial: wave = p-group (49 rows), lane = 8 cols (32B coalesced)
    const int col0 = ec * 512 + lane * 8;
    const float* ep = enc + (size_t)ord[b] * (P_ * ENC_) + (size_t)wave * 49 * ENC_ + col0;
    float s8[8] = {0.f, 0.f, 0.f, 0.f, 0.f, 0.f, 0.f, 0.f};
    for (int i = 0; i < 49; ++i) {
        float ap = esh[wave * 49 + i];
        float4 u0 = *reinterpret_cast<const float4*>(ep + (size_t)i * ENC_);
        float4 u1 = *reinterpret_cast<const float4*>(ep + (size_t)i * ENC_ + 4);
        s8[0] += ap * u0.x; s8[1] += ap * u0.y; s8[2] += ap * u0.z; s8[3] += ap * u0.w;
        s8[4] += ap * u1.x; s8[5] += ap * u1.y; s8[6] += ap * u1.z; s8[7] += ap * u1.w;
    }
#pragma unroll
    for (int j = 0; j < 8; ++j) part[wave][lane * 8 + j] = s8[j];
    __syncthreads();
    const int cc = tid * 2;
    float r0 = part[0][cc] + part[1][cc] + part[2][cc] + part[3][cc];
    float r1 = part[0][cc + 1] + part[1][cc + 1] + part[2][cc + 1] + part[3][cc + 1];
    const int col = ec * 512 + cc;
    float2 bt = *reinterpret_cast<const float2*>(&beta[b * 2048 + col]);
    unsigned pk = f2bf2(r0 * bt.x, r1 * bt.y);
    *reinterpret_cast<unsigned*>(XB + (size_t)b * XW_ + 512 + col) = pk;
}

// ============ fused z-GEMM + gates: 128 blocks x 512 thr, 8-way K-split ============
__global__ __launch_bounds__(512) void k_zgates(
    const ushort_t* __restrict__ XB_in, const ushort_t* __restrict__ WzP,
    const float* __restrict__ bl, const float* __restrict__ c_in,
    const int* __restrict__ slen, int t,
    float* __restrict__ c_out, ushort_t* __restrict__ cB_slot,
    ushort_t* __restrict__ XB_out)
{
    __shared__ float zsh[8][32][16];    // 16KB
    const int tid = threadIdx.x, lane = tid & 63, w = tid >> 6;   // w 0..7
    const int nt = blockIdx.x;          // 0..127: packed cols [nt*16, nt*16+16)
    const int kt0 = w * 12;             // wave = K-chunk of 384
    const int ar = lane & 15, ak = (lane >> 4) * 8;
    const ushort_t* A0 = XB_in + (size_t)ar * XW_ + kt0 * 32 + ak;
    const ushort_t* Bp = WzP + ((size_t)nt * 96 + kt0) * 512 + lane * 8;
    f32x4 acc0 = {}, acc1 = {};
#pragma unroll
    for (int kt = 0; kt < 12; ++kt) {
        bf16x8 a0 = *reinterpret_cast<const bf16x8*>(A0 + kt * 32);
        bf16x8 a1 = *reinterpret_cast<const bf16x8*>(A0 + 16 * XW_ + kt * 32);
        bf16x8 bf = *reinterpret_cast<const bf16x8*>(Bp + kt * 512);
        acc0 = __builtin_amdgcn_mfma_f32_16x16x32_bf16(a0, bf, acc0, 0, 0, 0);
        acc1 = __builtin_amdgcn_mfma_f32_16x16x32_bf16(a1, bf, acc1, 0, 0, 0);
    }
    const int col = lane & 15, r0 = (lane >> 4) * 4;
#pragma unroll
    for (int r = 0; r < 4; ++r) {
        zsh[w][r0 + r][col] = acc0[r];
        zsh[w][16 + r0 + r][col] = acc1[r];
    }
    __syncthreads();
    if (tid < 128) {
        const int b = tid >> 2, li = tid & 3;
        const int l = nt * 4 + li;
        float z[4];
#pragma unroll
        for (int g = 0; g < 4; ++g) {
            const int c = li * 4 + g;
            z[g] = zsh[0][b][c] + zsh[1][b][c] + zsh[2][b][c] + zsh[3][b][c]
                 + zsh[4][b][c] + zsh[5][b][c] + zsh[6][b][c] + zsh[7][b][c]
                 + bl[g * 512 + l];
        }
        float si = 1.f / (1.f + expf(-z[0]));
        float sf = 1.f / (1.f + expf(-z[1]));
        float gg = tanhf(z[2]);
        float so = 1.f / (1.f + expf(-z[3]));
        float cn = sf * c_in[b * 512 + l] + si * gg;
        float hn = so * tanhf(cn);
        float mf = (slen[b] > t) ? 1.f : 0.f;
        cn *= mf; hn *= mf;
        c_out[b * 512 + l] = cn;
        cB_slot[b * 512 + l] = f2bf(cn);
        XB_out[(size_t)b * XW_ + 2560 + l] = f2bf(hn);
    }
}

// ============ GEMM2-lite (MFMA): cB(32x512) @ [Wb|Wga]Pack -> beta, a2s; + emb gather ============
__global__ __launch_bounds__(256) void k_cmfma_lite(
    const ushort_t* __restrict__ cB, const ushort_t* __restrict__ WcP,
    const float* __restrict__ bb, const float* __restrict__ bga,
    int tnext, const int* __restrict__ seqs, const float* __restrict__ emb,
    const int* __restrict__ ord,
    float* __restrict__ beta, float* __restrict__ a2s, ushort_t* __restrict__ XB_out)
{
    const int bid = blockIdx.x, tid = threadIdx.x;
    if (bid >= 20) {
        const int g = (bid - 20) * 256 + tid;    // 0..511
        const int b = g >> 4, j0 = (g & 15) * 32;
        const int tok = seqs[ord[b] * T_ + tnext];
        const float4* src = reinterpret_cast<const float4*>(emb + (size_t)tok * E_ + j0);
        uint4* dst = reinterpret_cast<uint4*>(XB_out + (size_t)b * XW_ + j0);
#pragma unroll
        for (int q = 0; q < 4; ++q) {
            float4 v0 = src[2 * q], v1 = src[2 * q + 1];
            uint4 o;
            o.x = f2bf2(v0.x, v0.y); o.y = f2bf2(v0.z, v0.w);
            o.z = f2bf2(v1.x, v1.y); o.w = f2bf2(v1.z, v1.w);
            dst[q] = o;
        }
        return;
    }
    const int lane = tid & 63, w = tid >> 6;
    const int nt0 = bid * 8 + w * 2;                 // 0..158 (cols < 2560)
    const int ar = lane & 15, ak = (lane >> 4) * 8;
    const ushort_t* A0 = cB + ar * 512 + ak;
    const ushort_t* Bp = WcP + (size_t)nt0 * 8192 + lane * 8;
    f32x4 acc[2][2] = {};
    for (int kt = 0; kt < 16; ++kt) {
        bf16x8 a0 = *reinterpret_cast<const bf16x8*>(A0 + kt * 32);
        bf16x8 a1 = *reinterpret_cast<const bf16x8*>(A0 + 16 * 512 + kt * 32);
        bf16x8 b0 = *reinterpret_cast<const bf16x8*>(Bp + kt * 512);
        bf16x8 b1 = *reinterpret_cast<const bf16x8*>(Bp + 8192 + kt * 512);
        acc[0][0] = __builtin_amdgcn_mfma_f32_16x16x32_bf16(a0, b0, acc[0][0], 0, 0, 0);
        acc[0][1] = __builtin_amdgcn_mfma_f32_16x16x32_bf16(a0, b1, acc[0][1], 0, 0, 0);
        acc[1][0] = __builtin_amdgcn_mfma_f32_16x16x32_bf16(a1, b0, acc[1][0], 0, 0, 0);
        acc[1][1] = __builtin_amdgcn_mfma_f32_16x16x32_bf16(a1, b1, acc[1][1], 0, 0, 0);
    }
    const int r0 = (lane >> 4) * 4, cb2 = lane & 15;
#pragma unroll
    for (int nti = 0; nti < 2; ++nti) {
        const int n = (nt0 + nti) * 16 + cb2;
#pragma unroll
        for (int mt = 0; mt < 2; ++mt) {
#pragma unroll
            for (int r = 0; r < 4; ++r) {
                const int brow = mt * 16 + r0 + r;
                float v = acc[mt][nti][r];
                if (n < 2048) {
                    beta[brow * 2048 + n] = 1.f / (1.f + expf(-(v + bb[n])));
                } else {
                    a2s[brow * 512 + (n - 2048)] = v + bga[n - 2048];
                }
            }
        }
    }
}

// ============ batched pred GEMM: cBall(640x512) @ WoPack(512x10000) + bo, masked ============
__global__ __launch_bounds__(256) void k_pred(
    const ushort_t* __restrict__ cBall, const ushort_t* __restrict__ WcP,
    const float* __restrict__ bo, const int* __restrict__ slen,
    float* __restrict__ out_pred)
{
    const int tid = threadIdx.x, lane = tid & 63, w = tid >> 6;
    const int n0 = blockIdx.x * 128;
    const int m0 = blockIdx.y * 128;
    const int wm = (w >> 1) * 64, wn = (w & 1) * 64;
    const int ar = lane & 15, ak = (lane >> 4) * 8;
    const int ntb = (2560 + n0 + wn) >> 4;
    f32x4 acc[4][4] = {};
    for (int kt = 0; kt < 16; ++kt) {
        bf16x8 af[4], bfr[4];
#pragma unroll
        for (int mt = 0; mt < 4; ++mt)
            af[mt] = *reinterpret_cast<const bf16x8*>(
                cBall + (size_t)(m0 + wm + mt * 16 + ar) * 512 + kt * 32 + ak);
#pragma unroll
        for (int nt = 0; nt < 4; ++nt)
            bfr[nt] = *reinterpret_cast<const bf16x8*>(
                WcP + ((size_t)(ntb + nt) * 16 + kt) * 512 + lane * 8);
#pragma unroll
        for (int mt = 0; mt < 4; ++mt)
#pragma unroll
            for (int nt = 0; nt < 4; ++nt)
                acc[mt][nt] = __builtin_amdgcn_mfma_f32_16x16x32_bf16(
                    af[mt], bfr[nt], acc[mt][nt], 0, 0, 0);
    }
    const int r0 = (lane >> 4) * 4, cb = lane & 15;
#pragma unroll
    for (int nt = 0; nt < 4; ++nt) {
        const int n = n0 + wn + nt * 16 + cb;
        if (n < V_) {
            const float bv = bo[n];
#pragma unroll
            for (int mt = 0; mt < 4; ++mt) {
#pragma unroll
                for (int r = 0; r < 4; ++r) {
                    const int m = m0 + wm + mt * 16 + r0 + r;     // m = t*32 + b
                    const int tt = m >> 5, bb_ = m & 31;
                    const float mf = (slen[bb_] > tt) ? 1.f : 0.f;
                    out_pred[((size_t)bb_ * STEPS + tt) * V_ + n] =
                        (acc[mt][nt][r] + bv) * mf;
                }
            }
        }
    }
}

extern "C" void kernel_launch(void* const* d_in, const int* in_sizes, int n_in,
                              void* d_out, int out_size, void* d_ws, size_t ws_size,
                              hipStream_t stream)
{
    const float* enc  = (const float*)d_in[0];
    const int*   seqs = (const int*)  d_in[1];
    const float* emb  = (const float*)d_in[2];
    const float* Wea  = (const float*)d_in[3];
    const float* bea  = (const float*)d_in[4];
    const float* Wga  = (const float*)d_in[5];
    const float* bga  = (const float*)d_in[6];
    const float* Wfa  = (const float*)d_in[7];
    const float* bfa  = (const float*)d_in[8];
    const float* Wl   = (const float*)d_in[9];
    const float* Ul   = (const float*)d_in[10];
    const float* bl   = (const float*)d_in[11];
    const float* Wim  = (const float*)d_in[12];
    const float* bim  = (const float*)d_in[13];
    const float* Wic  = (const float*)d_in[14];
    const float* bic  = (const float*)d_in[15];
    const float* Wb   = (const float*)d_in[16];
    const float* bb   = (const float*)d_in[17];
    const float* Wo   = (const float*)d_in[18];
    const float* bo   = (const float*)d_in[19];

    float* out = (float*)d_out;
    float* ws  = (float*)d_ws;
    int* ord  = (int*)(ws + WS_ORD);
    int* slen = (int*)(ws + WS_SLEN);
    ushort_t* cB0   = (ushort_t*)(ws + WS_CB0);
    ushort_t* cBall = (ushort_t*)(ws + WS_CBALL);
    ushort_t* XB0   = (ushort_t*)(ws + WS_XB);
    ushort_t* XB1   = (ushort_t*)(ws + WS_XB) + (size_t)B_ * XW_;
    ushort_t* a1b   = (ushort_t*)(ws + WS_A1B);
    ushort_t* WzP   = (ushort_t*)(ws + WS_WZP);
    ushort_t* WcP   = (ushort_t*)(ws + WS_WCP);
    ushort_t* WeaT  = (ushort_t*)(ws + WS_WEAT);
    float* a2s  = ws + WS_A2S;
    float* beta = ws + WS_BETA;

    // ---- prologue (7 dispatches) ----
    k_order<<<1, 64, 0, stream>>>(seqs, ord, slen, out + OUT_ORDER);
    k_mean<<<256, 256, 0, stream>>>(enc, ord, ws + WS_MEAN);
    sg_both<<<dim3(2, 16, 4), 256, 0, stream>>>(ws + WS_MEAN, Wim, Wic, ws + WS_PH);
    k_h0c0<<<128, 256, 0, stream>>>(ws + WS_PH, bim, bic, ws + WS_CBUF, cB0, XB0);
    k_packAll<<<10336, 256, 0, stream>>>(Wea, Wl, Ul, Wb, Wga, Wo, WeaT, WzP, WcP);
    k_a1_mfma<<<dim3(98, 4), 256, 0, stream>>>(enc, WeaT, bea, ord, a1b);
    // prep for step 0: beta, a2s, emb(0) -> XB0 from c0
    k_cmfma_lite<<<22, 256, 0, stream>>>(cB0, WcP, bb, bga, 0, seqs, emb, ord,
                                         beta, a2s, XB0);

    // ---- decode steps: 3 dispatches/step (last step: 2) ----
    for (int t = 0; t < STEPS; ++t) {
        float* c_in  = ws + WS_CBUF + (t & 1) * (B_ * L_);
        float* c_out = ws + WS_CBUF + ((t + 1) & 1) * (B_ * L_);
        ushort_t* cB_slot = cBall + (size_t)t * (B_ * L_);
        ushort_t* xb_cur = (t & 1) ? XB1 : XB0;
        ushort_t* xb_nxt = (t & 1) ? XB0 : XB1;

        k_eawex<<<128, 256, 0, stream>>>(a2s, Wfa, bfa, a1b, enc, ord, slen, t,
                                         beta, out + OUT_ALPHA, xb_cur);
        k_zgates<<<128, 512, 0, stream>>>(xb_cur, WzP, bl, c_in, slen, t,
                                          c_out, cB_slot, xb_nxt);
        if (t < STEPS - 1)
            k_cmfma_lite<<<22, 256, 0, stream>>>(cB_slot, WcP, bb, bga, t + 1,
                                                 seqs, emb, ord, beta, a2s, xb_nxt);
    }
    // ---- batched prediction GEMM ----
    k_pred<<<dim3(79, 5), 256, 0, stream>>>(cBall, WcP, bo, slen, out + OUT_PRED);
}

// Round 7
// 919.960 us; speedup vs baseline: 3.0413x; 1.2466x over previous
//
#include <hip/hip_runtime.h>
#include <math.h>

#define B_    32
#define T_    21
#define STEPS 20
#define V_    10000
#define E_    512
#define A_    512
#define L_    512
#define P_    196
#define ENC_  2048
#define XW_   3072   // bf16 X' row: [emb(512) | awe*beta(2048) | h(512)]

// ---- workspace layout (float offsets), total 8,908,864 fl = 35.6 MB ----
#define WS_ORD    0
#define WS_SLEN   32
#define WS_CBUF   64        // 2*16384 fp32 c double-buffer
#define WS_CB0    32832     // bf16 32*512 (c0, prologue)      -> 4096 fl
#define WS_CBALL  36928     // bf16 20*32*512 (c per step)     -> 163840 fl
#define WS_XB     200768    // bf16 2 x 32*3072 (double-buffered) -> 98304 fl
#define WS_A2S    299072    // 32*512
#define WS_BETA   315456    // 32*2048
#define WS_ESH    380992    // 32*256 (unused, layout stability)
#define WS_A1B    389184    // bf16 6272*512 -> 1605632 fl
#define WS_WZP    1994816   // bf16 128nt*96kt*64*8 -> 3145728 fl
#define WS_WCP    5140544   // bf16 792nt*16kt*64*8 -> 3244032 fl
#define WS_WEAT   8384576   // bf16 512*2048 -> 524288 fl (end 8908864)
// prologue-only aliases (stream-ordered: dead before k_packAll writes WzP):
#define WS_MEAN   (WS_WZP)           // 65536 fl; dead after sg_both
#define WS_PH     (WS_WZP + 65536)   // 524288 fl; dead after k_h0c0

// ---- output layout (float offsets) ----
#define OUT_PRED  0
#define OUT_ALPHA 6400000
#define OUT_ORDER 6525440

typedef __attribute__((ext_vector_type(8))) short bf16x8;
typedef __attribute__((ext_vector_type(4))) float f32x4;
typedef unsigned short ushort_t;

__device__ inline unsigned f2bf2(float lo, float hi) {
    unsigned a = __float_as_uint(lo), b = __float_as_uint(hi);
    a = (a + 0x7FFFu + ((a >> 16) & 1u)) >> 16;
    b = (b + 0x7FFFu + ((b >> 16) & 1u)) >> 16;
    return a | (b << 16);
}
__device__ inline ushort_t f2bf(float f) {
    unsigned u = __float_as_uint(f);
    return (ushort_t)((u + 0x7FFFu + ((u >> 16) & 1u)) >> 16);
}
__device__ inline float bfu_lo(unsigned u) { return __uint_as_float(u << 16); }
__device__ inline float bfu_hi(unsigned u) { return __uint_as_float(u & 0xFFFF0000u); }

// ============ order / lengths ============
__global__ void k_order(const int* __restrict__ seqs, int* __restrict__ ord,
                        int* __restrict__ slen, float* __restrict__ out_ord)
{
    __shared__ int len[B_];
    int i = threadIdx.x;
    if (i < B_) {
        int c = 0;
        for (int t = 0; t < T_; ++t) c += (seqs[i * T_ + t] != 0) ? 1 : 0;
        len[i] = c;
    }
    __syncthreads();
    if (i < B_) {
        int li = len[i], r = 0;
        for (int j = 0; j < B_; ++j) {
            int lj = len[j];
            if (lj > li || (lj == li && j < i)) ++r;
        }
        ord[r] = i; slen[r] = li - 1; out_ord[r] = (float)i;
    }
}

// ============ mean-pool encoder (sorted) ============
__global__ void k_mean(const float* __restrict__ enc, const int* __restrict__ ord,
                       float* __restrict__ mean)
{
    int tid = blockIdx.x * 256 + threadIdx.x;
    int b = tid >> 11, e = tid & 2047;
    const float* row = enc + (size_t)ord[b] * (P_ * ENC_) + e;
    float s = 0.f;
    for (int p = 0; p < P_; ++p) s += row[(size_t)p * ENC_];
    mean[tid] = s * (1.0f / 196.0f);
}

// ============ prologue skinny GEMM partials for h0 AND c0 in one dispatch ============
__global__ void sg_both(const float* __restrict__ X, const float* __restrict__ Wim,
                        const float* __restrict__ Wic, float* __restrict__ part)
{
    const int n = blockIdx.x * 256 + threadIdx.x;
    const int c = blockIdx.y;
    const int bh = blockIdx.z & 1;
    const int which = blockIdx.z >> 1;
    const float* W = which ? Wic : Wim;
    const int chunk_ofs = which * 16;
    const int k0 = c * 128;
    const int k1 = k0 + 128;
    float acc[16];
#pragma unroll
    for (int b = 0; b < 16; ++b) acc[b] = 0.f;
    const float* Xb = X + (size_t)(bh * 16) * 2048;
    for (int k = k0; k < k1; k += 4) {
        float w0 = W[(size_t)(k + 0) * 512 + n];
        float w1 = W[(size_t)(k + 1) * 512 + n];
        float w2 = W[(size_t)(k + 2) * 512 + n];
        float w3 = W[(size_t)(k + 3) * 512 + n];
#pragma unroll
        for (int b = 0; b < 16; ++b) {
            const float4 xv = *reinterpret_cast<const float4*>(&Xb[(size_t)b * 2048 + k]);
            acc[b] += xv.x * w0 + xv.y * w1 + xv.z * w2 + xv.w * w3;
        }
    }
    float* po = part + (size_t)(chunk_ofs + c) * (B_ * 512) + (size_t)(bh * 16) * 512;
#pragma unroll
    for (int b = 0; b < 16; ++b) po[(size_t)b * 512 + n] = acc[b];
}

// ============ h0/c0 combine ============
__global__ void k_h0c0(const float* __restrict__ ph, const float* __restrict__ bim,
                       const float* __restrict__ bic, float* __restrict__ c0,
                       ushort_t* __restrict__ cB0, ushort_t* __restrict__ XB0)
{
    int tid = blockIdx.x * 256 + threadIdx.x;
    int half = tid >> 14;
    int idx = tid & 16383;
    int l = idx & 511, b = idx >> 9;
    int cofs = half ? 16 : 0;
    float s = 0.f;
    for (int c = 0; c < 16; ++c) s += ph[(size_t)(cofs + c) * (B_ * 512) + idx];
    if (half) {
        float cv = s + bic[l];
        c0[idx] = cv;
        cB0[idx] = f2bf(cv);
    } else {
        XB0[(size_t)b * XW_ + 2560 + l] = f2bf(s + bim[l]);
    }
}

// ============ all weight packing in one dispatch ============
__global__ void k_packAll(const float* __restrict__ Wea, const float* __restrict__ Wl,
                          const float* __restrict__ Ul, const float* __restrict__ Wb,
                          const float* __restrict__ Wga, const float* __restrict__ Wo,
                          ushort_t* __restrict__ WT, ushort_t* __restrict__ Wz,
                          ushort_t* __restrict__ Wc)
{
    const int bid = blockIdx.x;
    if (bid < 4096) {
        int tid = bid * 256 + threadIdx.x;
        int n = tid >> 11, k = tid & 2047;
        WT[tid] = f2bf(Wea[(size_t)k * 512 + n]);
    } else if (bid < 7168) {
        const unsigned tidg = (unsigned)(bid - 4096) * 256 + threadIdx.x;  // < 786432
        const int l = tidg & 63;
        const unsigned rem = tidg >> 6;
        const int kt = rem % 96;
        const int nt = rem / 96;
        const int k = kt * 32 + ((l >> 4) << 3);
        const int np = nt * 16 + (l & 15);
        const int n = (np & 3) * 512 + (np >> 2);   // gate-interleaved original col
        float v[8];
#pragma unroll
        for (int j = 0; j < 8; ++j) {
            int kr = k + j;
            v[j] = (kr < 2560) ? Wl[(size_t)kr * 2048 + n] : Ul[(size_t)(kr - 2560) * 2048 + n];
        }
        uint4 o;
        o.x = f2bf2(v[0], v[1]); o.y = f2bf2(v[2], v[3]);
        o.z = f2bf2(v[4], v[5]); o.w = f2bf2(v[6], v[7]);
        *reinterpret_cast<uint4*>(Wz + (size_t)tidg * 8) = o;
    } else {
        const unsigned tidg = (unsigned)(bid - 7168) * 256 + threadIdx.x;  // < 811008
        const int l = tidg & 63;
        const int kt = (tidg >> 6) & 15;
        const int nt = tidg >> 10;
        const int k = kt * 32 + ((l >> 4) << 3);
        const int n = nt * 16 + (l & 15);
        float v[8];
#pragma unroll
        for (int j = 0; j < 8; ++j) {
            int kr = k + j;
            float x;
            if (n < 2048)            x = Wb[(size_t)kr * 2048 + n];
            else if (n < 2560)       x = Wga[(size_t)kr * 512 + (n - 2048)];
            else if (n < 2560 + V_)  x = Wo[(size_t)kr * V_ + (n - 2560)];
            else                     x = 0.f;
            v[j] = x;
        }
        uint4 o;
        o.x = f2bf2(v[0], v[1]); o.y = f2bf2(v[2], v[3]);
        o.z = f2bf2(v[4], v[5]); o.w = f2bf2(v[6], v[7]);
        *reinterpret_cast<uint4*>(Wc + (size_t)tidg * 8) = o;
    }
}

// ============ a1 MFMA, 64-row M-tiles, grid (4,98): consecutive blocks share A-slab ============
__global__ __launch_bounds__(256) void k_a1_mfma(
    const float* __restrict__ enc, const ushort_t* __restrict__ WeaT,
    const float* __restrict__ bea, const int* __restrict__ ord,
    ushort_t* __restrict__ a1b)
{
    __shared__ ushort_t As[2][64 * 40];
    __shared__ ushort_t Bs[2][128 * 40];
    const int tid = threadIdx.x;
    const int lane = tid & 63, wave = tid >> 6;
    const int m0 = blockIdx.y * 64;       // swizzled: y = M-tile (slow), x = N-tile (fast)
    const int n0 = blockIdx.x * 128;

    const int arA = tid >> 2, akA = (tid & 3) * 8;
    const int gA = m0 + arA;
    const float* Ag = enc + ((size_t)ord[gA / P_] * P_ + (gA % P_)) * ENC_ + akA;
    const int cb0 = tid, cb1 = tid + 256;
    const ushort_t* Bg0 = WeaT + (size_t)(n0 + (cb0 >> 2)) * ENC_ + (cb0 & 3) * 8;
    const ushort_t* Bg1 = WeaT + (size_t)(n0 + (cb1 >> 2)) * ENC_ + (cb1 & 3) * 8;
    const int aoA  = arA * 40 + akA;
    const int aoB0 = (cb0 >> 2) * 40 + (cb0 & 3) * 8;
    const int aoB1 = (cb1 >> 2) * 40 + (cb1 & 3) * 8;

    const int wn = wave * 32;
    f32x4 acc[4][2] = {};

    {
        float4 v0 = *reinterpret_cast<const float4*>(Ag);
        float4 v1 = *reinterpret_cast<const float4*>(Ag + 4);
        uint4 pa;
        pa.x = f2bf2(v0.x, v0.y); pa.y = f2bf2(v0.z, v0.w);
        pa.z = f2bf2(v1.x, v1.y); pa.w = f2bf2(v1.z, v1.w);
        *reinterpret_cast<uint4*>(&As[0][aoA]) = pa;
        *reinterpret_cast<uint4*>(&Bs[0][aoB0]) = *reinterpret_cast<const uint4*>(Bg0);
        *reinterpret_cast<uint4*>(&Bs[0][aoB1]) = *reinterpret_cast<const uint4*>(Bg1);
    }
    __syncthreads();

    for (int it = 0; it < 64; ++it) {
        const int cur = it & 1;
        uint4 npa, npb0, npb1;
        const bool more = (it < 63);
        if (more) {
            const int k0 = (it + 1) * 32;
            float4 v0 = *reinterpret_cast<const float4*>(Ag + k0);
            float4 v1 = *reinterpret_cast<const float4*>(Ag + k0 + 4);
            npa.x = f2bf2(v0.x, v0.y); npa.y = f2bf2(v0.z, v0.w);
            npa.z = f2bf2(v1.x, v1.y); npa.w = f2bf2(v1.z, v1.w);
            npb0 = *reinterpret_cast<const uint4*>(Bg0 + k0);
            npb1 = *reinterpret_cast<const uint4*>(Bg1 + k0);
        }
        {
            bf16x8 af[4], bfr[2];
            const int arow = lane & 15;
            const int koff = (lane >> 4) * 8;
#pragma unroll
            for (int mt = 0; mt < 4; ++mt)
                af[mt] = *reinterpret_cast<const bf16x8*>(&As[cur][(arow + mt * 16) * 40 + koff]);
#pragma unroll
            for (int nt = 0; nt < 2; ++nt)
                bfr[nt] = *reinterpret_cast<const bf16x8*>(&Bs[cur][(wn + nt * 16 + arow) * 40 + koff]);
#pragma unroll
            for (int mt = 0; mt < 4; ++mt)
#pragma unroll
                for (int nt = 0; nt < 2; ++nt)
                    acc[mt][nt] = __builtin_amdgcn_mfma_f32_16x16x32_bf16(
                        af[mt], bfr[nt], acc[mt][nt], 0, 0, 0);
        }
        if (more) {
            const int nxt = cur ^ 1;
            *reinterpret_cast<uint4*>(&As[nxt][aoA]) = npa;
            *reinterpret_cast<uint4*>(&Bs[nxt][aoB0]) = npb0;
            *reinterpret_cast<uint4*>(&Bs[nxt][aoB1]) = npb1;
        }
        __syncthreads();
    }
    const int rbase = (lane >> 4) * 4;
    const int cbase = lane & 15;
#pragma unroll
    for (int nt = 0; nt < 2; ++nt) {
        int col = n0 + wn + nt * 16 + cbase;
        float be = bea[col];
#pragma unroll
        for (int mt = 0; mt < 4; ++mt) {
            int row = m0 + mt * 16 + rbase;
#pragma unroll
            for (int r = 0; r < 4; ++r)
                a1b[(size_t)(row + r) * 512 + col] = f2bf(acc[mt][nt][r] + be);
        }
    }
}

// ============ fused e + softmax + awe + beta-gate + x-write: 256 blocks (b x 8 ec of 256) ============
__global__ __launch_bounds__(256, 1) void k_eawex(
    const float* __restrict__ a2s, const float* __restrict__ Wfa,
    const float* __restrict__ bfa, const ushort_t* __restrict__ a1b,
    const float* __restrict__ enc, const int* __restrict__ ord,
    const int* __restrict__ slen, int t, const float* __restrict__ beta,
    float* __restrict__ out_alpha, ushort_t* __restrict__ XB)
{
    __shared__ float a2sh[512];
    __shared__ float wfsh[512];
    __shared__ float esh[208];
    __shared__ float red[256];
    __shared__ float part[4][256];
    const int b = blockIdx.x >> 3, ec = blockIdx.x & 7;
    const int tid = threadIdx.x;
    const int wave = tid >> 6, lane = tid & 63;
    a2sh[tid] = a2s[b * 512 + tid];       a2sh[tid + 256] = a2s[b * 512 + 256 + tid];
    wfsh[tid] = Wfa[tid];                 wfsh[tid + 256] = Wfa[256 + tid];
    __syncthreads();

    const int grp = lane >> 4, sub = lane & 15;
    float4 a2r[4][2], wfr[4][2];
#pragma unroll
    for (int blk = 0; blk < 4; ++blk)
#pragma unroll
        for (int j = 0; j < 2; ++j) {
            int d = blk * 128 + sub * 8 + j * 4;
            a2r[blk][j] = *reinterpret_cast<const float4*>(&a2sh[d]);
            wfr[blk][j] = *reinterpret_cast<const float4*>(&wfsh[d]);
        }
    const float bf0 = bfa[0];
    // e for all 196 p-rows: 13 passes of 16 rows
#pragma unroll
    for (int pass = 0; pass < 13; ++pass) {
        const int pl = pass * 16 + wave * 4 + grp;
        const bool valid = pl < P_;
        const int p = valid ? pl : 0;
        const ushort_t* arow = a1b + ((size_t)b * P_ + p) * 512;
        float s = 0.f;
#pragma unroll
        for (int blk = 0; blk < 4; ++blk) {
            uint4 raw = *reinterpret_cast<const uint4*>(arow + blk * 128 + sub * 8);
            float4 av = a2r[blk][0], wv = wfr[blk][0];
            float v;
            v = bfu_lo(raw.x) + av.x; v = v > 0.f ? v : 0.f; s += v * wv.x;
            v = bfu_hi(raw.x) + av.y; v = v > 0.f ? v : 0.f; s += v * wv.y;
            v = bfu_lo(raw.y) + av.z; v = v > 0.f ? v : 0.f; s += v * wv.z;
            v = bfu_hi(raw.y) + av.w; v = v > 0.f ? v : 0.f; s += v * wv.w;
            av = a2r[blk][1]; wv = wfr[blk][1];
            v = bfu_lo(raw.z) + av.x; v = v > 0.f ? v : 0.f; s += v * wv.x;
            v = bfu_hi(raw.z) + av.y; v = v > 0.f ? v : 0.f; s += v * wv.y;
            v = bfu_lo(raw.w) + av.z; v = v > 0.f ? v : 0.f; s += v * wv.z;
            v = bfu_hi(raw.w) + av.w; v = v > 0.f ? v : 0.f; s += v * wv.w;
        }
        s += __shfl_xor(s, 1, 64);
        s += __shfl_xor(s, 2, 64);
        s += __shfl_xor(s, 4, 64);
        s += __shfl_xor(s, 8, 64);
        if (sub == 0 && valid) esh[pl] = s + bf0;
    }
    __syncthreads();

    // softmax over esh[196]
    float v = (tid < P_) ? esh[tid] : -1e30f;
    red[tid] = v; __syncthreads();
    for (int s2 = 128; s2 > 0; s2 >>= 1) {
        if (tid < s2) red[tid] = fmaxf(red[tid], red[tid + s2]);
        __syncthreads();
    }
    float mx = red[0]; __syncthreads();
    float ex = (tid < P_) ? expf(v - mx) : 0.f;
    red[tid] = ex; __syncthreads();
    for (int s2 = 128; s2 > 0; s2 >>= 1) {
        if (tid < s2) red[tid] += red[tid + s2];
        __syncthreads();
    }
    float inv = 1.0f / red[0];
    float al = ex * inv;
    __syncthreads();
    if (tid < P_) esh[tid] = al;     // esh becomes alpha
    if (ec == 0 && tid < P_) {
        float mf = (slen[b] > t) ? 1.f : 0.f;
        out_alpha[((size_t)b * STEPS + t) * P_ + tid] = al * mf;
    }
    __syncthreads();

    // awe partial: wave = p-group (49 rows), lane = 4 cols (16B coalesced)
    const int col0 = ec * 256 + lane * 4;
    const float* ep = enc + (size_t)ord[b] * (P_ * ENC_) + (size_t)wave * 49 * ENC_ + col0;
    float s4[4] = {0.f, 0.f, 0.f, 0.f};
    for (int i = 0; i < 49; ++i) {
        float ap = esh[wave * 49 + i];
        float4 u = *reinterpret_cast<const float4*>(ep + (size_t)i * ENC_);
        s4[0] += ap * u.x; s4[1] += ap * u.y; s4[2] += ap * u.z; s4[3] += ap * u.w;
    }
#pragma unroll
    for (int j = 0; j < 4; ++j) part[wave][lane * 4 + j] = s4[j];
    __syncthreads();
    if (tid < 128) {
        const int cc = tid * 2;
        float r0 = part[0][cc] + part[1][cc] + part[2][cc] + part[3][cc];
        float r1 = part[0][cc + 1] + part[1][cc + 1] + part[2][cc + 1] + part[3][cc + 1];
        const int col = ec * 256 + cc;
        float2 bt = *reinterpret_cast<const float2*>(&beta[b * 2048 + col]);
        unsigned pk = f2bf2(r0 * bt.x, r1 * bt.y);
        *reinterpret_cast<unsigned*>(XB + (size_t)b * XW_ + 512 + col) = pk;
    }
}

// ============ fused z-GEMM + gates: 256 blocks x 512 thr (nt x 2 m-halves) ============
__global__ __launch_bounds__(512) void k_zgates(
    const ushort_t* __restrict__ XB_in, const ushort_t* __restrict__ WzP,
    const float* __restrict__ bl, const float* __restrict__ c_in,
    const int* __restrict__ slen, int t,
    float* __restrict__ c_out, ushort_t* __restrict__ cB_slot,
    ushort_t* __restrict__ XB_out)
{
    __shared__ float zsh[8][16][16];    // 8KB
    const int tid = threadIdx.x, lane = tid & 63, w = tid >> 6;   // w 0..7
    const int nt = blockIdx.x >> 1;     // 0..127: packed cols [nt*16, nt*16+16)
    const int mb = blockIdx.x & 1;      // m-half: rows mb*16..mb*16+15
    const int kt0 = w * 12;             // wave = K-chunk of 384 (same grouping as r6)
    const int ar = lane & 15, ak = (lane >> 4) * 8;
    const ushort_t* A0 = XB_in + (size_t)(mb * 16 + ar) * XW_ + kt0 * 32 + ak;
    const ushort_t* Bp = WzP + ((size_t)nt * 96 + kt0) * 512 + lane * 8;
    f32x4 acc0 = {};
#pragma unroll
    for (int kt = 0; kt < 12; ++kt) {
        bf16x8 a0 = *reinterpret_cast<const bf16x8*>(A0 + kt * 32);
        bf16x8 bf = *reinterpret_cast<const bf16x8*>(Bp + kt * 512);
        acc0 = __builtin_amdgcn_mfma_f32_16x16x32_bf16(a0, bf, acc0, 0, 0, 0);
    }
    const int col = lane & 15, r0 = (lane >> 4) * 4;
#pragma unroll
    for (int r = 0; r < 4; ++r) zsh[w][r0 + r][col] = acc0[r];
    __syncthreads();
    if (tid < 64) {
        const int bl_ = tid >> 2, li = tid & 3;
        const int b = mb * 16 + bl_;
        const int l = nt * 4 + li;
        float z[4];
#pragma unroll
        for (int g = 0; g < 4; ++g) {
            const int c = li * 4 + g;
            z[g] = zsh[0][bl_][c] + zsh[1][bl_][c] + zsh[2][bl_][c] + zsh[3][bl_][c]
                 + zsh[4][bl_][c] + zsh[5][bl_][c] + zsh[6][bl_][c] + zsh[7][bl_][c]
                 + bl[g * 512 + l];
        }
        float si = 1.f / (1.f + expf(-z[0]));
        float sf = 1.f / (1.f + expf(-z[1]));
        float gg = tanhf(z[2]);
        float so = 1.f / (1.f + expf(-z[3]));
        float cn = sf * c_in[b * 512 + l] + si * gg;
        float hn = so * tanhf(cn);
        float mf = (slen[b] > t) ? 1.f : 0.f;
        cn *= mf; hn *= mf;
        c_out[b * 512 + l] = cn;
        cB_slot[b * 512 + l] = f2bf(cn);
        XB_out[(size_t)b * XW_ + 2560 + l] = f2bf(hn);
    }
}

// ============ GEMM2-lite: 162 blocks (1 nt each, 4 waves split K) + emb gather ============
__global__ __launch_bounds__(256) void k_cmfma_lite(
    const ushort_t* __restrict__ cB, const ushort_t* __restrict__ WcP,
    const float* __restrict__ bb, const float* __restrict__ bga,
    int tnext, const int* __restrict__ seqs, const float* __restrict__ emb,
    const int* __restrict__ ord,
    float* __restrict__ beta, float* __restrict__ a2s, ushort_t* __restrict__ XB_out)
{
    __shared__ float zsh[4][32][16];    // 8KB
    const int bid = blockIdx.x, tid = threadIdx.x;
    if (bid >= 160) {
        const int g = (bid - 160) * 256 + tid;   // 0..511
        const int b = g >> 4, j0 = (g & 15) * 32;
        const int tok = seqs[ord[b] * T_ + tnext];
        const float4* src = reinterpret_cast<const float4*>(emb + (size_t)tok * E_ + j0);
        uint4* dst = reinterpret_cast<uint4*>(XB_out + (size_t)b * XW_ + j0);
#pragma unroll
        for (int q = 0; q < 4; ++q) {
            float4 v0 = src[2 * q], v1 = src[2 * q + 1];
            uint4 o;
            o.x = f2bf2(v0.x, v0.y); o.y = f2bf2(v0.z, v0.w);
            o.z = f2bf2(v1.x, v1.y); o.w = f2bf2(v1.z, v1.w);
            dst[q] = o;
        }
        return;
    }
    const int lane = tid & 63, w = tid >> 6;     // w 0..3: K-chunk of 128
    const int nt = bid;                           // cols nt*16..nt*16+15 (< 2560)
    const int ar = lane & 15, ak = (lane >> 4) * 8;
    const ushort_t* A0 = cB + ar * 512 + w * 128 + ak;
    const ushort_t* Bp = WcP + ((size_t)nt * 16 + w * 4) * 512 + lane * 8;
    f32x4 acc0 = {}, acc1 = {};
#pragma unroll
    for (int kt = 0; kt < 4; ++kt) {
        bf16x8 a0 = *reinterpret_cast<const bf16x8*>(A0 + kt * 32);
        bf16x8 a1 = *reinterpret_cast<const bf16x8*>(A0 + 16 * 512 + kt * 32);
        bf16x8 b0 = *reinterpret_cast<const bf16x8*>(Bp + kt * 512);
        acc0 = __builtin_amdgcn_mfma_f32_16x16x32_bf16(a0, b0, acc0, 0, 0, 0);
        acc1 = __builtin_amdgcn_mfma_f32_16x16x32_bf16(a1, b0, acc1, 0, 0, 0);
    }
    const int col = lane & 15, r0 = (lane >> 4) * 4;
#pragma unroll
    for (int r = 0; r < 4; ++r) {
        zsh[w][r0 + r][col] = acc0[r];
        zsh[w][16 + r0 + r][col] = acc1[r];
    }
    __syncthreads();
    if (tid < 256) {
#pragma unroll
        for (int half = 0; half < 2; ++half) {
            const int idx = tid + half * 256;
            if (idx < 512) {
                const int row = idx >> 4, cc = idx & 15;
                float v = zsh[0][row][cc] + zsh[1][row][cc] + zsh[2][row][cc] + zsh[3][row][cc];
                const int n = nt * 16 + cc;
                if (n < 2048) {
                    beta[row * 2048 + n] = 1.f / (1.f + expf(-(v + bb[n])));
                } else {
                    a2s[row * 512 + (n - 2048)] = v + bga[n - 2048];
                }
            }
        }
    }
}

// ============ batched pred GEMM: cBall(640x512) @ WoPack(512x10000) + bo, masked ============
__global__ __launch_bounds__(256) void k_pred(
    const ushort_t* __restrict__ cBall, const ushort_t* __restrict__ WcP,
    const float* __restrict__ bo, const int* __restrict__ slen,
    float* __restrict__ out_pred)
{
    const int tid = threadIdx.x, lane = tid & 63, w = tid >> 6;
    const int n0 = blockIdx.x * 128;
    const int m0 = blockIdx.y * 128;
    const int wm = (w >> 1) * 64, wn = (w & 1) * 64;
    const int ar = lane & 15, ak = (lane >> 4) * 8;
    const int ntb = (2560 + n0 + wn) >> 4;
    f32x4 acc[4][4] = {};
    for (int kt = 0; kt < 16; ++kt) {
        bf16x8 af[4], bfr[4];
#pragma unroll
        for (int mt = 0; mt < 4; ++mt)
            af[mt] = *reinterpret_cast<const bf16x8*>(
                cBall + (size_t)(m0 + wm + mt * 16 + ar) * 512 + kt * 32 + ak);
#pragma unroll
        for (int nt = 0; nt < 4; ++nt)
            bfr[nt] = *reinterpret_cast<const bf16x8*>(
                WcP + ((size_t)(ntb + nt) * 16 + kt) * 512 + lane * 8);
#pragma unroll
        for (int mt = 0; mt < 4; ++mt)
#pragma unroll
            for (int nt = 0; nt < 4; ++nt)
                acc[mt][nt] = __builtin_amdgcn_mfma_f32_16x16x32_bf16(
                    af[mt], bfr[nt], acc[mt][nt], 0, 0, 0);
    }
    const int r0 = (lane >> 4) * 4, cb = lane & 15;
#pragma unroll
    for (int nt = 0; nt < 4; ++nt) {
        const int n = n0 + wn + nt * 16 + cb;
        if (n < V_) {
            const float bv = bo[n];
#pragma unroll
            for (int mt = 0; mt < 4; ++mt) {
#pragma unroll
                for (int r = 0; r < 4; ++r) {
                    const int m = m0 + wm + mt * 16 + r0 + r;     // m = t*32 + b
                    const int tt = m >> 5, bb_ = m & 31;
                    const float mf = (slen[bb_] > tt) ? 1.f : 0.f;
                    out_pred[((size_t)bb_ * STEPS + tt) * V_ + n] =
                        (acc[mt][nt][r] + bv) * mf;
                }
            }
        }
    }
}

extern "C" void kernel_launch(void* const* d_in, const int* in_sizes, int n_in,
                              void* d_out, int out_size, void* d_ws, size_t ws_size,
                              hipStream_t stream)
{
    const float* enc  = (const float*)d_in[0];
    const int*   seqs = (const int*)  d_in[1];
    const float* emb  = (const float*)d_in[2];
    const float* Wea  = (const float*)d_in[3];
    const float* bea  = (const float*)d_in[4];
    const float* Wga  = (const float*)d_in[5];
    const float* bga  = (const float*)d_in[6];
    const float* Wfa  = (const float*)d_in[7];
    const float* bfa  = (const float*)d_in[8];
    const float* Wl   = (const float*)d_in[9];
    const float* Ul   = (const float*)d_in[10];
    const float* bl   = (const float*)d_in[11];
    const float* Wim  = (const float*)d_in[12];
    const float* bim  = (const float*)d_in[13];
    const float* Wic  = (const float*)d_in[14];
    const float* bic  = (const float*)d_in[15];
    const float* Wb   = (const float*)d_in[16];
    const float* bb   = (const float*)d_in[17];
    const float* Wo   = (const float*)d_in[18];
    const float* bo   = (const float*)d_in[19];

    float* out = (float*)d_out;
    float* ws  = (float*)d_ws;
    int* ord  = (int*)(ws + WS_ORD);
    int* slen = (int*)(ws + WS_SLEN);
    ushort_t* cB0   = (ushort_t*)(ws + WS_CB0);
    ushort_t* cBall = (ushort_t*)(ws + WS_CBALL);
    ushort_t* XB0   = (ushort_t*)(ws + WS_XB);
    ushort_t* XB1   = (ushort_t*)(ws + WS_XB) + (size_t)B_ * XW_;
    ushort_t* a1b   = (ushort_t*)(ws + WS_A1B);
    ushort_t* WzP   = (ushort_t*)(ws + WS_WZP);
    ushort_t* WcP   = (ushort_t*)(ws + WS_WCP);
    ushort_t* WeaT  = (ushort_t*)(ws + WS_WEAT);
    float* a2s  = ws + WS_A2S;
    float* beta = ws + WS_BETA;

    // ---- prologue (7 dispatches) ----
    k_order<<<1, 64, 0, stream>>>(seqs, ord, slen, out + OUT_ORDER);
    k_mean<<<256, 256, 0, stream>>>(enc, ord, ws + WS_MEAN);
    sg_both<<<dim3(2, 16, 4), 256, 0, stream>>>(ws + WS_MEAN, Wim, Wic, ws + WS_PH);
    k_h0c0<<<128, 256, 0, stream>>>(ws + WS_PH, bim, bic, ws + WS_CBUF, cB0, XB0);
    k_packAll<<<10336, 256, 0, stream>>>(Wea, Wl, Ul, Wb, Wga, Wo, WeaT, WzP, WcP);
    k_a1_mfma<<<dim3(4, 98), 256, 0, stream>>>(enc, WeaT, bea, ord, a1b);
    k_cmfma_lite<<<162, 256, 0, stream>>>(cB0, WcP, bb, bga, 0, seqs, emb, ord,
                                          beta, a2s, XB0);

    // ---- decode steps: 3 dispatches/step (last step: 2) ----
    for (int t = 0; t < STEPS; ++t) {
        float* c_in  = ws + WS_CBUF + (t & 1) * (B_ * L_);
        float* c_out = ws + WS_CBUF + ((t + 1) & 1) * (B_ * L_);
        ushort_t* cB_slot = cBall + (size_t)t * (B_ * L_);
        ushort_t* xb_cur = (t & 1) ? XB1 : XB0;
        ushort_t* xb_nxt = (t & 1) ? XB0 : XB1;

        k_eawex<<<256, 256, 0, stream>>>(a2s, Wfa, bfa, a1b, enc, ord, slen, t,
                                         beta, out + OUT_ALPHA, xb_cur);
        k_zgates<<<256, 512, 0, stream>>>(xb_cur, WzP, bl, c_in, slen, t,
                                          c_out, cB_slot, xb_nxt);
        if (t < STEPS - 1)
            k_cmfma_lite<<<162, 256, 0, stream>>>(cB_slot, WcP, bb, bga, t + 1,
                                                  seqs, emb, ord, beta, a2s, xb_nxt);
    }
    // ---- batched prediction GEMM ----
    k_pred<<<dim3(79, 5), 256, 0, stream>>>(cBall, WcP, bo, slen, out + OUT_PRED);
}

// Round 8
// 918.983 us; speedup vs baseline: 3.0445x; 1.0011x over previous
//
#include <hip/hip_runtime.h>
#include <math.h>

#define B_    32
#define T_    21
#define STEPS 20
#define V_    10000
#define E_    512
#define A_    512
#define L_    512
#define P_    196
#define ENC_  2048
#define XW_   3072   // bf16 X' row: [emb(512) | awe*beta(2048) | h(512)]

// ---- workspace layout (float offsets), total 8,908,864 fl = 35.6 MB ----
#define WS_ORD    0
#define WS_SLEN   32
#define WS_CBUF   64        // 2*16384 fp32 c double-buffer
#define WS_CB0    32832     // bf16 32*512 (c0, prologue)      -> 4096 fl
#define WS_CBALL  36928     // bf16 20*32*512 (c per step)     -> 163840 fl
#define WS_XB     200768    // bf16 2 x 32*3072 (double-buffered) -> 98304 fl
#define WS_A2S    299072    // 32*512
#define WS_BETA   315456    // 32*2048
#define WS_ESH    380992    // 32*256 (unused, layout stability)
#define WS_A1B    389184    // bf16 6272*512 -> 1605632 fl
#define WS_WZP    1994816   // bf16 128nt*96kt*64*8 -> 3145728 fl
#define WS_WCP    5140544   // bf16 792nt*16kt*64*8 -> 3244032 fl
#define WS_WEAT   8384576   // bf16 512*2048 -> 524288 fl (end 8908864)
// prologue-only aliases (stream-ordered: dead before k_packAll writes WzP):
#define WS_MEAN   (WS_WZP)           // 65536 fl; dead after sg_both
#define WS_PH     (WS_WZP + 65536)   // 524288 fl; dead after k_h0c0

// ---- output layout (float offsets) ----
#define OUT_PRED  0
#define OUT_ALPHA 6400000
#define OUT_ORDER 6525440

typedef __attribute__((ext_vector_type(8))) short bf16x8;
typedef __attribute__((ext_vector_type(4))) float f32x4;
typedef unsigned short ushort_t;

__device__ inline unsigned f2bf2(float lo, float hi) {
    unsigned a = __float_as_uint(lo), b = __float_as_uint(hi);
    a = (a + 0x7FFFu + ((a >> 16) & 1u)) >> 16;
    b = (b + 0x7FFFu + ((b >> 16) & 1u)) >> 16;
    return a | (b << 16);
}
__device__ inline ushort_t f2bf(float f) {
    unsigned u = __float_as_uint(f);
    return (ushort_t)((u + 0x7FFFu + ((u >> 16) & 1u)) >> 16);
}
__device__ inline float bfu_lo(unsigned u) { return __uint_as_float(u << 16); }
__device__ inline float bfu_hi(unsigned u) { return __uint_as_float(u & 0xFFFF0000u); }

// ============ order / lengths ============
__global__ void k_order(const int* __restrict__ seqs, int* __restrict__ ord,
                        int* __restrict__ slen, float* __restrict__ out_ord)
{
    __shared__ int len[B_];
    int i = threadIdx.x;
    if (i < B_) {
        int c = 0;
        for (int t = 0; t < T_; ++t) c += (seqs[i * T_ + t] != 0) ? 1 : 0;
        len[i] = c;
    }
    __syncthreads();
    if (i < B_) {
        int li = len[i], r = 0;
        for (int j = 0; j < B_; ++j) {
            int lj = len[j];
            if (lj > li || (lj == li && j < i)) ++r;
        }
        ord[r] = i; slen[r] = li - 1; out_ord[r] = (float)i;
    }
}

// ============ mean-pool encoder (sorted) ============
__global__ void k_mean(const float* __restrict__ enc, const int* __restrict__ ord,
                       float* __restrict__ mean)
{
    int tid = blockIdx.x * 256 + threadIdx.x;
    int b = tid >> 11, e = tid & 2047;
    const float* row = enc + (size_t)ord[b] * (P_ * ENC_) + e;
    float s = 0.f;
    for (int p = 0; p < P_; ++p) s += row[(size_t)p * ENC_];
    mean[tid] = s * (1.0f / 196.0f);
}

// ============ prologue skinny GEMM partials for h0 AND c0 in one dispatch ============
__global__ void sg_both(const float* __restrict__ X, const float* __restrict__ Wim,
                        const float* __restrict__ Wic, float* __restrict__ part)
{
    const int n = blockIdx.x * 256 + threadIdx.x;
    const int c = blockIdx.y;
    const int bh = blockIdx.z & 1;
    const int which = blockIdx.z >> 1;
    const float* W = which ? Wic : Wim;
    const int chunk_ofs = which * 16;
    const int k0 = c * 128;
    const int k1 = k0 + 128;
    float acc[16];
#pragma unroll
    for (int b = 0; b < 16; ++b) acc[b] = 0.f;
    const float* Xb = X + (size_t)(bh * 16) * 2048;
    for (int k = k0; k < k1; k += 4) {
        float w0 = W[(size_t)(k + 0) * 512 + n];
        float w1 = W[(size_t)(k + 1) * 512 + n];
        float w2 = W[(size_t)(k + 2) * 512 + n];
        float w3 = W[(size_t)(k + 3) * 512 + n];
#pragma unroll
        for (int b = 0; b < 16; ++b) {
            const float4 xv = *reinterpret_cast<const float4*>(&Xb[(size_t)b * 2048 + k]);
            acc[b] += xv.x * w0 + xv.y * w1 + xv.z * w2 + xv.w * w3;
        }
    }
    float* po = part + (size_t)(chunk_ofs + c) * (B_ * 512) + (size_t)(bh * 16) * 512;
#pragma unroll
    for (int b = 0; b < 16; ++b) po[(size_t)b * 512 + n] = acc[b];
}

// ============ h0/c0 combine ============
__global__ void k_h0c0(const float* __restrict__ ph, const float* __restrict__ bim,
                       const float* __restrict__ bic, float* __restrict__ c0,
                       ushort_t* __restrict__ cB0, ushort_t* __restrict__ XB0)
{
    int tid = blockIdx.x * 256 + threadIdx.x;
    int half = tid >> 14;
    int idx = tid & 16383;
    int l = idx & 511, b = idx >> 9;
    int cofs = half ? 16 : 0;
    float s = 0.f;
    for (int c = 0; c < 16; ++c) s += ph[(size_t)(cofs + c) * (B_ * 512) + idx];
    if (half) {
        float cv = s + bic[l];
        c0[idx] = cv;
        cB0[idx] = f2bf(cv);
    } else {
        XB0[(size_t)b * XW_ + 2560 + l] = f2bf(s + bim[l]);
    }
}

// ============ all weight packing in one dispatch ============
__global__ void k_packAll(const float* __restrict__ Wea, const float* __restrict__ Wl,
                          const float* __restrict__ Ul, const float* __restrict__ Wb,
                          const float* __restrict__ Wga, const float* __restrict__ Wo,
                          ushort_t* __restrict__ WT, ushort_t* __restrict__ Wz,
                          ushort_t* __restrict__ Wc)
{
    const int bid = blockIdx.x;
    if (bid < 4096) {
        int tid = bid * 256 + threadIdx.x;
        int n = tid >> 11, k = tid & 2047;
        WT[tid] = f2bf(Wea[(size_t)k * 512 + n]);
    } else if (bid < 7168) {
        const unsigned tidg = (unsigned)(bid - 4096) * 256 + threadIdx.x;  // < 786432
        const int l = tidg & 63;
        const unsigned rem = tidg >> 6;
        const int kt = rem % 96;
        const int nt = rem / 96;
        const int k = kt * 32 + ((l >> 4) << 3);
        const int np = nt * 16 + (l & 15);
        const int n = (np & 3) * 512 + (np >> 2);   // gate-interleaved original col
        float v[8];
#pragma unroll
        for (int j = 0; j < 8; ++j) {
            int kr = k + j;
            v[j] = (kr < 2560) ? Wl[(size_t)kr * 2048 + n] : Ul[(size_t)(kr - 2560) * 2048 + n];
        }
        uint4 o;
        o.x = f2bf2(v[0], v[1]); o.y = f2bf2(v[2], v[3]);
        o.z = f2bf2(v[4], v[5]); o.w = f2bf2(v[6], v[7]);
        *reinterpret_cast<uint4*>(Wz + (size_t)tidg * 8) = o;
    } else {
        const unsigned tidg = (unsigned)(bid - 7168) * 256 + threadIdx.x;  // < 811008
        const int l = tidg & 63;
        const int kt = (tidg >> 6) & 15;
        const int nt = tidg >> 10;
        const int k = kt * 32 + ((l >> 4) << 3);
        const int n = nt * 16 + (l & 15);
        float v[8];
#pragma unroll
        for (int j = 0; j < 8; ++j) {
            int kr = k + j;
            float x;
            if (n < 2048)            x = Wb[(size_t)kr * 2048 + n];
            else if (n < 2560)       x = Wga[(size_t)kr * 512 + (n - 2048)];
            else if (n < 2560 + V_)  x = Wo[(size_t)kr * V_ + (n - 2560)];
            else                     x = 0.f;
            v[j] = x;
        }
        uint4 o;
        o.x = f2bf2(v[0], v[1]); o.y = f2bf2(v[2], v[3]);
        o.z = f2bf2(v[4], v[5]); o.w = f2bf2(v[6], v[7]);
        *reinterpret_cast<uint4*>(Wc + (size_t)tidg * 8) = o;
    }
}

// ============ a1 MFMA, 32-row M-tiles, grid (4,196) = 784 blocks (~3/CU) ============
__global__ __launch_bounds__(256) void k_a1_mfma(
    const float* __restrict__ enc, const ushort_t* __restrict__ WeaT,
    const float* __restrict__ bea, const int* __restrict__ ord,
    ushort_t* __restrict__ a1b)
{
    __shared__ ushort_t As[2][32 * 40];
    __shared__ ushort_t Bs[2][128 * 40];
    const int tid = threadIdx.x;
    const int lane = tid & 63, wave = tid >> 6;
    const int m0 = blockIdx.y * 32;       // y = M-tile (slow), x = N-tile (fast)
    const int n0 = blockIdx.x * 128;

    // A staging: 32 rows x 32 k = 128 chunks of 8 -> threads 0..127 stage one each
    const bool doA = tid < 128;
    const int arA = (tid & 127) >> 2, akA = (tid & 3) * 8;
    const int gA = m0 + arA;
    const float* Ag = enc + ((size_t)ord[gA / P_] * P_ + (gA % P_)) * ENC_ + akA;
    // B staging: 128 rows x 32 k = 512 chunks -> two per thread
    const int cb0 = tid, cb1 = tid + 256;
    const ushort_t* Bg0 = WeaT + (size_t)(n0 + (cb0 >> 2)) * ENC_ + (cb0 & 3) * 8;
    const ushort_t* Bg1 = WeaT + (size_t)(n0 + (cb1 >> 2)) * ENC_ + (cb1 & 3) * 8;
    const int aoA  = arA * 40 + akA;
    const int aoB0 = (cb0 >> 2) * 40 + (cb0 & 3) * 8;
    const int aoB1 = (cb1 >> 2) * 40 + (cb1 & 3) * 8;

    const int wn = wave * 32;
    f32x4 acc[2][2] = {};

    {
        if (doA) {
            float4 v0 = *reinterpret_cast<const float4*>(Ag);
            float4 v1 = *reinterpret_cast<const float4*>(Ag + 4);
            uint4 pa;
            pa.x = f2bf2(v0.x, v0.y); pa.y = f2bf2(v0.z, v0.w);
            pa.z = f2bf2(v1.x, v1.y); pa.w = f2bf2(v1.z, v1.w);
            *reinterpret_cast<uint4*>(&As[0][aoA]) = pa;
        }
        *reinterpret_cast<uint4*>(&Bs[0][aoB0]) = *reinterpret_cast<const uint4*>(Bg0);
        *reinterpret_cast<uint4*>(&Bs[0][aoB1]) = *reinterpret_cast<const uint4*>(Bg1);
    }
    __syncthreads();

    for (int it = 0; it < 64; ++it) {
        const int cur = it & 1;
        uint4 npa, npb0, npb1;
        const bool more = (it < 63);
        if (more) {
            const int k0 = (it + 1) * 32;
            if (doA) {
                float4 v0 = *reinterpret_cast<const float4*>(Ag + k0);
                float4 v1 = *reinterpret_cast<const float4*>(Ag + k0 + 4);
                npa.x = f2bf2(v0.x, v0.y); npa.y = f2bf2(v0.z, v0.w);
                npa.z = f2bf2(v1.x, v1.y); npa.w = f2bf2(v1.z, v1.w);
            }
            npb0 = *reinterpret_cast<const uint4*>(Bg0 + k0);
            npb1 = *reinterpret_cast<const uint4*>(Bg1 + k0);
        }
        {
            bf16x8 af[2], bfr[2];
            const int arow = lane & 15;
            const int koff = (lane >> 4) * 8;
#pragma unroll
            for (int mt = 0; mt < 2; ++mt)
                af[mt] = *reinterpret_cast<const bf16x8*>(&As[cur][(arow + mt * 16) * 40 + koff]);
#pragma unroll
            for (int nt = 0; nt < 2; ++nt)
                bfr[nt] = *reinterpret_cast<const bf16x8*>(&Bs[cur][(wn + nt * 16 + arow) * 40 + koff]);
#pragma unroll
            for (int mt = 0; mt < 2; ++mt)
#pragma unroll
                for (int nt = 0; nt < 2; ++nt)
                    acc[mt][nt] = __builtin_amdgcn_mfma_f32_16x16x32_bf16(
                        af[mt], bfr[nt], acc[mt][nt], 0, 0, 0);
        }
        if (more) {
            const int nxt = cur ^ 1;
            if (doA) *reinterpret_cast<uint4*>(&As[nxt][aoA]) = npa;
            *reinterpret_cast<uint4*>(&Bs[nxt][aoB0]) = npb0;
            *reinterpret_cast<uint4*>(&Bs[nxt][aoB1]) = npb1;
        }
        __syncthreads();
    }
    const int rbase = (lane >> 4) * 4;
    const int cbase = lane & 15;
#pragma unroll
    for (int nt = 0; nt < 2; ++nt) {
        int col = n0 + wn + nt * 16 + cbase;
        float be = bea[col];
#pragma unroll
        for (int mt = 0; mt < 2; ++mt) {
            int row = m0 + mt * 16 + rbase;
#pragma unroll
            for (int r = 0; r < 4; ++r)
                a1b[(size_t)(row + r) * 512 + col] = f2bf(acc[mt][nt][r] + be);
        }
    }
}

// ============ fused e + softmax + awe + beta-gate + x-write: 256 blocks x 512 thr ============
// block (b, ec of 8): e-phase 7 passes (8 waves x 4 rows), awe 8 p-groups of <=25 rows
__global__ __launch_bounds__(512, 1) void k_eawex(
    const float* __restrict__ a2s, const float* __restrict__ Wfa,
    const float* __restrict__ bfa, const ushort_t* __restrict__ a1b,
    const float* __restrict__ enc, const int* __restrict__ ord,
    const int* __restrict__ slen, int t, const float* __restrict__ beta,
    float* __restrict__ out_alpha, ushort_t* __restrict__ XB)
{
    __shared__ float a2sh[512];
    __shared__ float wfsh[512];
    __shared__ float esh[208];
    __shared__ float red[256];
    __shared__ float part[8][256];
    const int b = blockIdx.x >> 3, ec = blockIdx.x & 7;
    const int tid = threadIdx.x;
    const int wave = tid >> 6, lane = tid & 63;
    a2sh[tid] = a2s[b * 512 + tid];
    wfsh[tid] = Wfa[tid];
    __syncthreads();

    const int grp = lane >> 4, sub = lane & 15;
    float4 a2r[4][2], wfr[4][2];
#pragma unroll
    for (int blk = 0; blk < 4; ++blk)
#pragma unroll
        for (int j = 0; j < 2; ++j) {
            int d = blk * 128 + sub * 8 + j * 4;
            a2r[blk][j] = *reinterpret_cast<const float4*>(&a2sh[d]);
            wfr[blk][j] = *reinterpret_cast<const float4*>(&wfsh[d]);
        }
    const float bf0 = bfa[0];
    // e for all 196 p-rows: 7 passes of 32 rows (8 waves x 4 groups)
#pragma unroll
    for (int pass = 0; pass < 7; ++pass) {
        const int pl = pass * 32 + wave * 4 + grp;
        const bool valid = pl < P_;
        const int p = valid ? pl : 0;
        const ushort_t* arow = a1b + ((size_t)b * P_ + p) * 512;
        float s = 0.f;
#pragma unroll
        for (int blk = 0; blk < 4; ++blk) {
            uint4 raw = *reinterpret_cast<const uint4*>(arow + blk * 128 + sub * 8);
            float4 av = a2r[blk][0], wv = wfr[blk][0];
            float v;
            v = bfu_lo(raw.x) + av.x; v = v > 0.f ? v : 0.f; s += v * wv.x;
            v = bfu_hi(raw.x) + av.y; v = v > 0.f ? v : 0.f; s += v * wv.y;
            v = bfu_lo(raw.y) + av.z; v = v > 0.f ? v : 0.f; s += v * wv.z;
            v = bfu_hi(raw.y) + av.w; v = v > 0.f ? v : 0.f; s += v * wv.w;
            av = a2r[blk][1]; wv = wfr[blk][1];
            v = bfu_lo(raw.z) + av.x; v = v > 0.f ? v : 0.f; s += v * wv.x;
            v = bfu_hi(raw.z) + av.y; v = v > 0.f ? v : 0.f; s += v * wv.y;
            v = bfu_lo(raw.w) + av.z; v = v > 0.f ? v : 0.f; s += v * wv.z;
            v = bfu_hi(raw.w) + av.w; v = v > 0.f ? v : 0.f; s += v * wv.w;
        }
        s += __shfl_xor(s, 1, 64);
        s += __shfl_xor(s, 2, 64);
        s += __shfl_xor(s, 4, 64);
        s += __shfl_xor(s, 8, 64);
        if (sub == 0 && valid) esh[pl] = s + bf0;
    }
    __syncthreads();

    // softmax over esh[196] (reduction on first 256 threads; all 512 hit barriers)
    float v = (tid < P_) ? esh[tid] : -1e30f;
    if (tid < 256) red[tid] = v;
    __syncthreads();
    for (int s2 = 128; s2 > 0; s2 >>= 1) {
        if (tid < s2) red[tid] = fmaxf(red[tid], red[tid + s2]);
        __syncthreads();
    }
    float mx = red[0]; __syncthreads();
    float ex = (tid < P_) ? expf(v - mx) : 0.f;
    if (tid < 256) red[tid] = ex;
    __syncthreads();
    for (int s2 = 128; s2 > 0; s2 >>= 1) {
        if (tid < s2) red[tid] += red[tid + s2];
        __syncthreads();
    }
    float inv = 1.0f / red[0];
    float al = ex * inv;
    __syncthreads();
    if (tid < P_) esh[tid] = al;     // esh becomes alpha
    if (ec == 0 && tid < P_) {
        float mf = (slen[b] > t) ? 1.f : 0.f;
        out_alpha[((size_t)b * STEPS + t) * P_ + tid] = al * mf;
    }
    __syncthreads();

    // awe partial: wave = p-group (<=25 rows), lane = 4 cols (16B coalesced)
    const int row0 = wave * 25;
    const int cnt = (row0 + 25 <= P_) ? 25 : (P_ - row0);   // wave 7: 21
    const int col0 = ec * 256 + lane * 4;
    const float* ep = enc + (size_t)ord[b] * (P_ * ENC_) + (size_t)row0 * ENC_ + col0;
    float s4[4] = {0.f, 0.f, 0.f, 0.f};
    for (int i = 0; i < cnt; ++i) {
        float ap = esh[row0 + i];
        float4 u = *reinterpret_cast<const float4*>(ep + (size_t)i * ENC_);
        s4[0] += ap * u.x; s4[1] += ap * u.y; s4[2] += ap * u.z; s4[3] += ap * u.w;
    }
#pragma unroll
    for (int j = 0; j < 4; ++j) part[wave][lane * 4 + j] = s4[j];
    __syncthreads();
    if (tid < 128) {
        const int cc = tid * 2;
        float r0 = part[0][cc] + part[1][cc] + part[2][cc] + part[3][cc]
                 + part[4][cc] + part[5][cc] + part[6][cc] + part[7][cc];
        float r1 = part[0][cc + 1] + part[1][cc + 1] + part[2][cc + 1] + part[3][cc + 1]
                 + part[4][cc + 1] + part[5][cc + 1] + part[6][cc + 1] + part[7][cc + 1];
        const int col = ec * 256 + cc;
        float2 bt = *reinterpret_cast<const float2*>(&beta[b * 2048 + col]);
        unsigned pk = f2bf2(r0 * bt.x, r1 * bt.y);
        *reinterpret_cast<unsigned*>(XB + (size_t)b * XW_ + 512 + col) = pk;
    }
}

// ============ fused z-GEMM + gates: 256 blocks x 512 thr (nt x 2 m-halves) ============
__global__ __launch_bounds__(512) void k_zgates(
    const ushort_t* __restrict__ XB_in, const ushort_t* __restrict__ WzP,
    const float* __restrict__ bl, const float* __restrict__ c_in,
    const int* __restrict__ slen, int t,
    float* __restrict__ c_out, ushort_t* __restrict__ cB_slot,
    ushort_t* __restrict__ XB_out)
{
    __shared__ float zsh[8][16][16];    // 8KB
    const int tid = threadIdx.x, lane = tid & 63, w = tid >> 6;   // w 0..7
    const int nt = blockIdx.x >> 1;     // 0..127: packed cols [nt*16, nt*16+16)
    const int mb = blockIdx.x & 1;      // m-half: rows mb*16..mb*16+15
    const int kt0 = w * 12;             // wave = K-chunk of 384
    const int ar = lane & 15, ak = (lane >> 4) * 8;
    const ushort_t* A0 = XB_in + (size_t)(mb * 16 + ar) * XW_ + kt0 * 32 + ak;
    const ushort_t* Bp = WzP + ((size_t)nt * 96 + kt0) * 512 + lane * 8;
    f32x4 acc0 = {};
#pragma unroll
    for (int kt = 0; kt < 12; ++kt) {
        bf16x8 a0 = *reinterpret_cast<const bf16x8*>(A0 + kt * 32);
        bf16x8 bf = *reinterpret_cast<const bf16x8*>(Bp + kt * 512);
        acc0 = __builtin_amdgcn_mfma_f32_16x16x32_bf16(a0, bf, acc0, 0, 0, 0);
    }
    const int col = lane & 15, r0 = (lane >> 4) * 4;
#pragma unroll
    for (int r = 0; r < 4; ++r) zsh[w][r0 + r][col] = acc0[r];
    __syncthreads();
    if (tid < 64) {
        const int bl_ = tid >> 2, li = tid & 3;
        const int b = mb * 16 + bl_;
        const int l = nt * 4 + li;
        float z[4];
#pragma unroll
        for (int g = 0; g < 4; ++g) {
            const int c = li * 4 + g;
            z[g] = zsh[0][bl_][c] + zsh[1][bl_][c] + zsh[2][bl_][c] + zsh[3][bl_][c]
                 + zsh[4][bl_][c] + zsh[5][bl_][c] + zsh[6][bl_][c] + zsh[7][bl_][c]
                 + bl[g * 512 + l];
        }
        float si = 1.f / (1.f + expf(-z[0]));
        float sf = 1.f / (1.f + expf(-z[1]));
        float gg = tanhf(z[2]);
        float so = 1.f / (1.f + expf(-z[3]));
        float cn = sf * c_in[b * 512 + l] + si * gg;
        float hn = so * tanhf(cn);
        float mf = (slen[b] > t) ? 1.f : 0.f;
        cn *= mf; hn *= mf;
        c_out[b * 512 + l] = cn;
        cB_slot[b * 512 + l] = f2bf(cn);
        XB_out[(size_t)b * XW_ + 2560 + l] = f2bf(hn);
    }
}

// ============ GEMM2-lite: 322 blocks (nt x 2 m-halves, 4 waves split K) + emb gather ============
__global__ __launch_bounds__(256) void k_cmfma_lite(
    const ushort_t* __restrict__ cB, const ushort_t* __restrict__ WcP,
    const float* __restrict__ bb, const float* __restrict__ bga,
    int tnext, const int* __restrict__ seqs, const float* __restrict__ emb,
    const int* __restrict__ ord,
    float* __restrict__ beta, float* __restrict__ a2s, ushort_t* __restrict__ XB_out)
{
    __shared__ float zsh[4][16][16];    // 4KB
    const int bid = blockIdx.x, tid = threadIdx.x;
    if (bid >= 320) {
        const int g = (bid - 320) * 256 + tid;   // 0..511
        const int b = g >> 4, j0 = (g & 15) * 32;
        const int tok = seqs[ord[b] * T_ + tnext];
        const float4* src = reinterpret_cast<const float4*>(emb + (size_t)tok * E_ + j0);
        uint4* dst = reinterpret_cast<uint4*>(XB_out + (size_t)b * XW_ + j0);
#pragma unroll
        for (int q = 0; q < 4; ++q) {
            float4 v0 = src[2 * q], v1 = src[2 * q + 1];
            uint4 o;
            o.x = f2bf2(v0.x, v0.y); o.y = f2bf2(v0.z, v0.w);
            o.z = f2bf2(v1.x, v1.y); o.w = f2bf2(v1.z, v1.w);
            dst[q] = o;
        }
        return;
    }
    const int lane = tid & 63, w = tid >> 6;     // w 0..3: K-chunk of 128
    const int nt = bid >> 1;                      // cols nt*16..nt*16+15 (< 2560)
    const int mb = bid & 1;                       // rows mb*16..mb*16+15
    const int ar = lane & 15, ak = (lane >> 4) * 8;
    const ushort_t* A0 = cB + (mb * 16 + ar) * 512 + w * 128 + ak;
    const ushort_t* Bp = WcP + ((size_t)nt * 16 + w * 4) * 512 + lane * 8;
    f32x4 acc0 = {};
#pragma unroll
    for (int kt = 0; kt < 4; ++kt) {
        bf16x8 a0 = *reinterpret_cast<const bf16x8*>(A0 + kt * 32);
        bf16x8 b0 = *reinterpret_cast<const bf16x8*>(Bp + kt * 512);
        acc0 = __builtin_amdgcn_mfma_f32_16x16x32_bf16(a0, b0, acc0, 0, 0, 0);
    }
    const int col = lane & 15, r0 = (lane >> 4) * 4;
#pragma unroll
    for (int r = 0; r < 4; ++r) zsh[w][r0 + r][col] = acc0[r];
    __syncthreads();
    {
        const int row = tid >> 4, cc = tid & 15;   // 256 threads = 16 rows x 16 cols
        float v = zsh[0][row][cc] + zsh[1][row][cc] + zsh[2][row][cc] + zsh[3][row][cc];
        const int brow = mb * 16 + row;
        const int n = nt * 16 + cc;
        if (n < 2048) {
            beta[brow * 2048 + n] = 1.f / (1.f + expf(-(v + bb[n])));
        } else {
            a2s[brow * 512 + (n - 2048)] = v + bga[n - 2048];
        }
    }
}

// ============ batched pred GEMM: cBall(640x512) @ WoPack(512x10000) + bo, masked ============
__global__ __launch_bounds__(256) void k_pred(
    const ushort_t* __restrict__ cBall, const ushort_t* __restrict__ WcP,
    const float* __restrict__ bo, const int* __restrict__ slen,
    float* __restrict__ out_pred)
{
    const int tid = threadIdx.x, lane = tid & 63, w = tid >> 6;
    const int n0 = blockIdx.x * 128;
    const int m0 = blockIdx.y * 128;
    const int wm = (w >> 1) * 64, wn = (w & 1) * 64;
    const int ar = lane & 15, ak = (lane >> 4) * 8;
    const int ntb = (2560 + n0 + wn) >> 4;
    f32x4 acc[4][4] = {};
    for (int kt = 0; kt < 16; ++kt) {
        bf16x8 af[4], bfr[4];
#pragma unroll
        for (int mt = 0; mt < 4; ++mt)
            af[mt] = *reinterpret_cast<const bf16x8*>(
                cBall + (size_t)(m0 + wm + mt * 16 + ar) * 512 + kt * 32 + ak);
#pragma unroll
        for (int nt = 0; nt < 4; ++nt)
            bfr[nt] = *reinterpret_cast<const bf16x8*>(
                WcP + ((size_t)(ntb + nt) * 16 + kt) * 512 + lane * 8);
#pragma unroll
        for (int mt = 0; mt < 4; ++mt)
#pragma unroll
            for (int nt = 0; nt < 4; ++nt)
                acc[mt][nt] = __builtin_amdgcn_mfma_f32_16x16x32_bf16(
                    af[mt], bfr[nt], acc[mt][nt], 0, 0, 0);
    }
    const int r0 = (lane >> 4) * 4, cb = lane & 15;
#pragma unroll
    for (int nt = 0; nt < 4; ++nt) {
        const int n = n0 + wn + nt * 16 + cb;
        if (n < V_) {
            const float bv = bo[n];
#pragma unroll
            for (int mt = 0; mt < 4; ++mt) {
#pragma unroll
                for (int r = 0; r < 4; ++r) {
                    const int m = m0 + wm + mt * 16 + r0 + r;     // m = t*32 + b
                    const int tt = m >> 5, bb_ = m & 31;
                    const float mf = (slen[bb_] > tt) ? 1.f : 0.f;
                    out_pred[((size_t)bb_ * STEPS + tt) * V_ + n] =
                        (acc[mt][nt][r] + bv) * mf;
                }
            }
        }
    }
}

extern "C" void kernel_launch(void* const* d_in, const int* in_sizes, int n_in,
                              void* d_out, int out_size, void* d_ws, size_t ws_size,
                              hipStream_t stream)
{
    const float* enc  = (const float*)d_in[0];
    const int*   seqs = (const int*)  d_in[1];
    const float* emb  = (const float*)d_in[2];
    const float* Wea  = (const float*)d_in[3];
    const float* bea  = (const float*)d_in[4];
    const float* Wga  = (const float*)d_in[5];
    const float* bga  = (const float*)d_in[6];
    const float* Wfa  = (const float*)d_in[7];
    const float* bfa  = (const float*)d_in[8];
    const float* Wl   = (const float*)d_in[9];
    const float* Ul   = (const float*)d_in[10];
    const float* bl   = (const float*)d_in[11];
    const float* Wim  = (const float*)d_in[12];
    const float* bim  = (const float*)d_in[13];
    const float* Wic  = (const float*)d_in[14];
    const float* bic  = (const float*)d_in[15];
    const float* Wb   = (const float*)d_in[16];
    const float* bb   = (const float*)d_in[17];
    const float* Wo   = (const float*)d_in[18];
    const float* bo   = (const float*)d_in[19];

    float* out = (float*)d_out;
    float* ws  = (float*)d_ws;
    int* ord  = (int*)(ws + WS_ORD);
    int* slen = (int*)(ws + WS_SLEN);
    ushort_t* cB0   = (ushort_t*)(ws + WS_CB0);
    ushort_t* cBall = (ushort_t*)(ws + WS_CBALL);
    ushort_t* XB0   = (ushort_t*)(ws + WS_XB);
    ushort_t* XB1   = (ushort_t*)(ws + WS_XB) + (size_t)B_ * XW_;
    ushort_t* a1b   = (ushort_t*)(ws + WS_A1B);
    ushort_t* WzP   = (ushort_t*)(ws + WS_WZP);
    ushort_t* WcP   = (ushort_t*)(ws + WS_WCP);
    ushort_t* WeaT  = (ushort_t*)(ws + WS_WEAT);
    float* a2s  = ws + WS_A2S;
    float* beta = ws + WS_BETA;

    // ---- prologue (7 dispatches) ----
    k_order<<<1, 64, 0, stream>>>(seqs, ord, slen, out + OUT_ORDER);
    k_mean<<<256, 256, 0, stream>>>(enc, ord, ws + WS_MEAN);
    sg_both<<<dim3(2, 16, 4), 256, 0, stream>>>(ws + WS_MEAN, Wim, Wic, ws + WS_PH);
    k_h0c0<<<128, 256, 0, stream>>>(ws + WS_PH, bim, bic, ws + WS_CBUF, cB0, XB0);
    k_packAll<<<10336, 256, 0, stream>>>(Wea, Wl, Ul, Wb, Wga, Wo, WeaT, WzP, WcP);
    k_a1_mfma<<<dim3(4, 196), 256, 0, stream>>>(enc, WeaT, bea, ord, a1b);
    k_cmfma_lite<<<322, 256, 0, stream>>>(cB0, WcP, bb, bga, 0, seqs, emb, ord,
                                          beta, a2s, XB0);

    // ---- decode steps: 3 dispatches/step (last step: 2) ----
    for (int t = 0; t < STEPS; ++t) {
        float* c_in  = ws + WS_CBUF + (t & 1) * (B_ * L_);
        float* c_out = ws + WS_CBUF + ((t + 1) & 1) * (B_ * L_);
        ushort_t* cB_slot = cBall + (size_t)t * (B_ * L_);
        ushort_t* xb_cur = (t & 1) ? XB1 : XB0;
        ushort_t* xb_nxt = (t & 1) ? XB0 : XB1;

        k_eawex<<<256, 512, 0, stream>>>(a2s, Wfa, bfa, a1b, enc, ord, slen, t,
                                         beta, out + OUT_ALPHA, xb_cur);
        k_zgates<<<256, 512, 0, stream>>>(xb_cur, WzP, bl, c_in, slen, t,
                                          c_out, cB_slot, xb_nxt);
        if (t < STEPS - 1)
            k_cmfma_lite<<<322, 256, 0, stream>>>(cB_slot, WcP, bb, bga, t + 1,
                                                  seqs, emb, ord, beta, a2s, xb_nxt);
    }
    // ---- batched prediction GEMM ----
    k_pred<<<dim3(79, 5), 256, 0, stream>>>(cBall, WcP, bo, slen, out + OUT_PRED);
}